// Round 16
// baseline (12188.412 us; speedup 1.0000x reference)
//
#include <hip/hip_runtime.h>

// ---------------------------------------------------------------------------
// TacotronMelDecoder on MI355X (gfx950) — precision-hardened persistent scan.
// R16 = R15 with FLAT rendezvous: arrive = single group fetch_add (8 x 64B
// counters, 32 arrivers each); wait = 8 threads poll the group counters
// directly for 32*ep (B-sets poll their 2 groups). Removes the root-RMW and
// release-store hops (4 MALL hops -> 2) from every one of the 1200 in-loop
// rendezvous. Phases/pipeline/rolling buffers identical to R15.
// ---------------------------------------------------------------------------

typedef unsigned short us16;
typedef unsigned int u32;
typedef unsigned long long u64;
typedef __attribute__((ext_vector_type(8))) short bf16x8;
typedef __attribute__((ext_vector_type(4))) float f32x4;

#define MFMA16 __builtin_amdgcn_mfma_f32_16x16x32_bf16
#define AGT __HIP_MEMORY_SCOPE_AGENT

__device__ __forceinline__ us16 f2bf(float f){
  u32 u = __builtin_bit_cast(u32, f);
  u += 0x7fffu + ((u >> 16) & 1u);
  return (us16)(u >> 16);
}
__device__ __forceinline__ float bf2f(us16 h){
  return __builtin_bit_cast(float, ((u32)h) << 16);
}
__device__ __forceinline__ float h2f(us16 u){
  _Float16 h = __builtin_bit_cast(_Float16, u); return (float)h;
}
__device__ __forceinline__ us16 f2h(float f){
  _Float16 h = (_Float16)f; return __builtin_bit_cast(us16, h);
}
__device__ __forceinline__ void split3(float v, us16& s0, us16& s1, us16& s2){
  s0 = f2bf(v); float r = v - bf2f(s0);
  s1 = f2bf(r); r -= bf2f(s1);
  s2 = f2bf(r);
}
__device__ __forceinline__ float tanh_fast(float x){
  float e = __expf(-2.f * fmaxf(x, -40.f));
  return (1.f - e) / (1.f + e);
}
__device__ __forceinline__ float sigf(float x){
  return 1.f / (1.f + __expf(-x));
}

__device__ __forceinline__ u32 aload32(const u32* p){
  return __hip_atomic_load(p, __ATOMIC_RELAXED, AGT);
}
__device__ __forceinline__ void astore16(us16* p, us16 v){
  __hip_atomic_store(p, v, __ATOMIC_RELAXED, AGT);
}
__device__ __forceinline__ void astoref(float* p, float v){
  __hip_atomic_store(p, v, __ATOMIC_RELAXED, AGT);
}
__device__ __forceinline__ void aaddf(float* p, float v){
  __hip_atomic_fetch_add(p, v, __ATOMIC_RELAXED, AGT);
}
__device__ __forceinline__ bf16x8 ld16(const us16* p){
  return *(const bf16x8*)p;
}
// opacity: keep a loaded fragment in regs (non-rematerializable)
__device__ __forceinline__ bf16x8 pin_reg(bf16x8 v){
  f32x4 t = __builtin_bit_cast(f32x4, v);
  asm volatile("" : "+v"(t));
  return __builtin_bit_cast(bf16x8, t);
}
// 8 cached fp32 -> scaled triple-split bf16 fragments (ctx path)
__device__ __forceinline__ void f32_frag3(const float* p, float rs,
                                          bf16x8& f0, bf16x8& f1, bf16x8& f2){
  float4 t0 = *(const float4*)p;
  float4 t1 = *(const float4*)(p + 4);
  float tf[8] = {t0.x, t0.y, t0.z, t0.w, t1.x, t1.y, t1.z, t1.w};
#pragma unroll
  for (int i = 0; i < 8; ++i){
    float v = tf[i] * rs;
    us16 s0, s1, s2; split3(v, s0, s1, s2);
    f0[i] = (short)s0; f1[i] = (short)s1; f2[i] = (short)s2;
  }
}

// ---------------- workspace layout (bytes) ----------------
#define OFF_WTA    0ull            // 3 planes [4096][2048] bf16 (cols permuted u*4+gate)
#define OFF_WQT    50331648ull     // 3 planes [1024][1024] bf16 (Wq^T)
#define OFF_X2P    56623104ull     // 3 planes [32*200][512] bf16 (prenet out)
#define OFF_KEYH   76283904ull     // [8192][1024] fp16 hi
#define OFF_KEYL   93061120ull     // [8192][1024] fp16 lo
#define OFF_X1     76283904ull     // alias over KEYH/KEYL (dead before keys written)
#define OFF_HPR    129597440ull    // [201][3][32][1024] bf16 h planes (rolling)
#define OFF_UCR    169115648ull    // [201][32][512] f32 raw ctx sums (rolling, atomics)
#define OFF_SR     182288384ull    // [201][32] f32 softmax sums (rolling; slot0=1)
#define OFF_CB     182314112ull    // [32][1024] f32 c state (block-private)
#define OFF_HF     182445184ull    // [32][1024] f32 final h (plain)
#define OFF_WAPN   182576256ull    // [1536][80] bf16 (Wa@Wp natural)
#define OFF_BPERM  182822016ull    // [4096] f32
#define OFF_ARR    182838400ull    // sync: 6 sets x 8 group counters (64B apart)
#define OFF_QR     182870016ull    // [200][32][1024] f32 q (rolling)
#define TOTAL_WS   209094656ull

#define WTPL 8388608ull
#define WQPL 1048576ull
#define X2PL 3276800ull

// sync sets
#define SA0 0
#define SA1 1
#define SB0 2
#define SB1 3
#define SC0 4
#define SC1 5

// ---------------- init + bperm (merged; re-run every launch: replay-safe) ----
__global__ void k_init(u32* hpr0, float* ucr, float* sr, float* cbuf, u32* arr,
                       const float* __restrict__ bl, float* __restrict__ bpm){
  u32 id = blockIdx.x * 256u + threadIdx.x;
  const u32 gs = 65536u;
  for (u32 i = id; i < 49152u;   i += gs) hpr0[i] = 0u;     // hp slot 0 (3 planes)
  for (u32 i = id; i < 3293184u; i += gs) ucr[i]  = 0.f;
  for (u32 i = id; i < 6432u;    i += gs) sr[i]   = (i < 32u) ? 1.f : 0.f;
  for (u32 i = id; i < 32768u;   i += gs) cbuf[i] = 0.f;
  for (u32 i = id; i < 2048u;    i += gs) arr[i]  = 0u;
  if (id < 4096u) bpm[((id & 1023u) << 2) | (id >> 10)] = bl[id];
}

// ---------------- transpose f32 -> 3 bf16 planes (+optional gate perm) ----------------
__global__ void k_transp3(const float* __restrict__ src, us16* __restrict__ dst,
                          int srows, int scols, int ldd, long long pstride, int perm){
  __shared__ float tile[32][33];
  int bx = blockIdx.x * 32, by = blockIdx.y * 32;
  int tx = threadIdx.x & 31, ty = threadIdx.x >> 5;
#pragma unroll
  for (int i = 0; i < 4; ++i){
    int r = by + ty + i * 8, c = bx + tx;
    tile[ty + i * 8][tx] = (r < srows && c < scols) ? src[(size_t)r * scols + c] : 0.f;
  }
  __syncthreads();
#pragma unroll
  for (int i = 0; i < 4; ++i){
    int c = bx + ty + i * 8;
    int r = by + tx;
    if (c < scols && r < srows){
      int oc = perm ? (((c & 1023) << 2) | (c >> 10)) : c;
      float v = tile[tx][ty + i * 8];
      us16 s0, s1, s2; split3(v, s0, s1, s2);
      size_t base = (size_t)oc * ldd + r;
      dst[base] = s0; dst[(size_t)pstride + base] = s1; dst[2ull * pstride + base] = s2;
    }
  }
}

// ---------------- generic triple-split GEMM: C[M,N] = A[M,K] @ B[K,N] ----------------
// AF/BF: 0 = bf16 single plane | 1 = f32, split on the fly
// modes: 0 f32+bias+relu | 1 relu -> x2 triple planes | 2 keys fp16 pair
//        3 fold -> WTA planes (+Wh, perm) | 4 bf16 plain
template<int NP, int AF, int BF>
__global__ void __launch_bounds__(256)
k_gemm3(const void* __restrict__ Ap, const void* __restrict__ Bp, void* __restrict__ outp,
        int M, int N, int K, int mode, const float* __restrict__ aux, int ldd){
  __shared__ us16 At[NP][128][72];
  __shared__ us16 Bt[NP][64][72];
  const int tid = threadIdx.x, wv = tid >> 6, lane = tid & 63;
  const int r0 = lane & 15, kg = lane >> 4;
  const int rb = blockIdx.x * 128, cb = blockIdx.y * 64;
  f32x4 acc[2][4];
#pragma unroll
  for (int a = 0; a < 2; ++a)
#pragma unroll
    for (int b = 0; b < 4; ++b) acc[a][b] = (f32x4){0.f, 0.f, 0.f, 0.f};

  const int nkt = (K + 63) >> 6;
  for (int kt = 0; kt < nkt; ++kt){
    const int kb = kt * 64;
    for (int e = tid; e < 8192; e += 256){
      int r = e >> 6, k = e & 63, ga = rb + r, gk = kb + k;
      bool ok = (ga < M) && (gk < K);
      if constexpr (AF == 1){
        float v = ok ? ((const float*)Ap)[(size_t)ga * K + gk] : 0.f;
        us16 s0, s1, s2; split3(v, s0, s1, s2);
        At[0][r][k] = s0;
        if constexpr (NP == 3){ At[1][r][k] = s1; At[2][r][k] = s2; }
      } else {
        At[0][r][k] = ok ? ((const us16*)Ap)[(size_t)ga * K + gk] : (us16)0;
      }
    }
    for (int e = tid; e < 4096; e += 256){
      int kr = e >> 6, c = e & 63, gk = kb + kr, gc = cb + c;
      bool ok = (gk < K) && (gc < N);
      if constexpr (BF == 1){
        float v = ok ? ((const float*)Bp)[(size_t)gk * N + gc] : 0.f;
        us16 s0, s1, s2; split3(v, s0, s1, s2);
        Bt[0][c][kr] = s0;
        if constexpr (NP == 3){ Bt[1][c][kr] = s1; Bt[2][c][kr] = s2; }
      } else {
        Bt[0][c][kr] = ok ? ((const us16*)Bp)[(size_t)gk * N + gc] : (us16)0;
      }
    }
    __syncthreads();
#pragma unroll
    for (int kk = 0; kk < 64; kk += 32){
      bf16x8 af[NP][2];
#pragma unroll
      for (int p = 0; p < NP; ++p){
        af[p][0] = *(const bf16x8*)&At[p][wv * 32 + r0][kk + kg * 8];
        af[p][1] = *(const bf16x8*)&At[p][wv * 32 + 16 + r0][kk + kg * 8];
      }
#pragma unroll
      for (int cf = 0; cf < 4; ++cf){
        bf16x8 bv[NP];
#pragma unroll
        for (int p = 0; p < NP; ++p) bv[p] = *(const bf16x8*)&Bt[p][cf * 16 + r0][kk + kg * 8];
#pragma unroll
        for (int rf = 0; rf < 2; ++rf){
          acc[rf][cf] = MFMA16(af[0][rf], bv[0], acc[rf][cf], 0, 0, 0);
          if constexpr (NP == 3){
            acc[rf][cf] = MFMA16(af[0][rf], bv[1], acc[rf][cf], 0, 0, 0);
            acc[rf][cf] = MFMA16(af[1][rf], bv[0], acc[rf][cf], 0, 0, 0);
            acc[rf][cf] = MFMA16(af[0][rf], bv[2], acc[rf][cf], 0, 0, 0);
            acc[rf][cf] = MFMA16(af[1][rf], bv[1], acc[rf][cf], 0, 0, 0);
            acc[rf][cf] = MFMA16(af[2][rf], bv[0], acc[rf][cf], 0, 0, 0);
          }
        }
      }
    }
    __syncthreads();
  }
  us16* o16 = (us16*)outp; float* of = (float*)outp;
#pragma unroll
  for (int rf = 0; rf < 2; ++rf)
#pragma unroll
    for (int cf = 0; cf < 4; ++cf)
#pragma unroll
      for (int i = 0; i < 4; ++i){
        int r = rb + wv * 32 + rf * 16 + kg * 4 + i;
        int c = cb + cf * 16 + r0;
        if (r >= M || c >= N) continue;
        float v = acc[rf][cf][i];
        if (mode == 0){
          of[(size_t)r * ldd + c] = fmaxf(v + aux[c], 0.f);
        } else if (mode == 1){
          v = fmaxf(v + aux[c], 0.f);
          us16 s0, s1, s2; split3(v, s0, s1, s2);
          size_t b2 = (size_t)r * ldd + c;
          o16[b2] = s0; o16[X2PL + b2] = s1; o16[2 * X2PL + b2] = s2;
        } else if (mode == 2){
          us16 hh = f2h(v); float rem = v - h2f(hh); us16 hl = f2h(rem);
          size_t b2 = (size_t)r * 1024 + c;
          o16[b2] = hh; o16[WTPL + b2] = hl;
        } else if (mode == 3){
          float w = v + (r < 1024 ? aux[(size_t)r * 4096 + c] : 0.f);
          int pc = (c & 1023) * 4 + (c >> 10);
          us16 s0, s1, s2; split3(w, s0, s1, s2);
          size_t b2 = (size_t)pc * 2048 + 512 + r;
          o16[b2] = s0; o16[WTPL + b2] = s1; o16[2 * WTPL + b2] = s2;
        } else {
          o16[(size_t)r * ldd + c] = f2bf(v);
        }
      }
}

// ---------------- epilogue GEMM: A staged from rolling state buffers ----------
template<int BF>
__global__ void __launch_bounds__(256)
k_gemmE(const us16* __restrict__ hpr, const float* __restrict__ ucr,
        const float* __restrict__ sr, const void* __restrict__ Bp,
        float* __restrict__ of, int M, int N, int K, int mode,
        const float* __restrict__ aux, int ldd, int ro){
  __shared__ us16 At[128][72];
  __shared__ us16 Bt[64][72];
  const int tid = threadIdx.x, wv = tid >> 6, lane = tid & 63;
  const int r0 = lane & 15, kg = lane >> 4;
  const int rb = blockIdx.x * 128, cb = blockIdx.y * 64;
  f32x4 acc[2][4];
#pragma unroll
  for (int a = 0; a < 2; ++a)
#pragma unroll
    for (int b = 0; b < 4; ++b) acc[a][b] = (f32x4){0.f, 0.f, 0.f, 0.f};

  const int nkt = (K + 63) >> 6;
  for (int kt = 0; kt < nkt; ++kt){
    const int kb = kt * 64;
    for (int e = tid; e < 8192; e += 256){
      int r = e >> 6, k = e & 63, ga = rb + r, gk = kb + k;
      us16 v = 0;
      if (ga < M && gk < K){
        int row = ro + ga, t = row >> 5, b = row & 31;
        if (gk < 1024){
          v = hpr[(size_t)t * 98304 + b * 1024 + gk];
        } else {
          float rs = 1.f / sr[(size_t)t * 32 + b];
          v = f2bf(ucr[(size_t)t * 16384 + b * 512 + (gk - 1024)] * rs);
        }
      }
      At[r][k] = v;
    }
    for (int e = tid; e < 4096; e += 256){
      int kr = e >> 6, c = e & 63, gk = kb + kr, gc = cb + c;
      bool ok = (gk < K) && (gc < N);
      if constexpr (BF == 1){
        float v = ok ? ((const float*)Bp)[(size_t)gk * N + gc] : 0.f;
        Bt[c][kr] = f2bf(v);
      } else {
        Bt[c][kr] = ok ? ((const us16*)Bp)[(size_t)gk * N + gc] : (us16)0;
      }
    }
    __syncthreads();
#pragma unroll
    for (int kk = 0; kk < 64; kk += 32){
      bf16x8 a0 = *(const bf16x8*)&At[wv * 32 + r0][kk + kg * 8];
      bf16x8 a1 = *(const bf16x8*)&At[wv * 32 + 16 + r0][kk + kg * 8];
#pragma unroll
      for (int cf = 0; cf < 4; ++cf){
        bf16x8 bv = *(const bf16x8*)&Bt[cf * 16 + r0][kk + kg * 8];
        acc[0][cf] = MFMA16(a0, bv, acc[0][cf], 0, 0, 0);
        acc[1][cf] = MFMA16(a1, bv, acc[1][cf], 0, 0, 0);
      }
    }
    __syncthreads();
  }
#pragma unroll
  for (int rf = 0; rf < 2; ++rf)
#pragma unroll
    for (int cf = 0; cf < 4; ++cf)
#pragma unroll
      for (int i = 0; i < 4; ++i){
        int r = rb + wv * 32 + rf * 16 + kg * 4 + i;
        int c = cb + cf * 16 + r0;
        if (r >= M || c >= N) continue;
        float v = acc[rf][cf][i];
        if (mode == 5){
          of[((size_t)(r & 31) * 200 + (r >> 5)) * 80 + c] = v + aux[c];
        } else {
          of[(size_t)r * ldd + c] = v;
        }
      }
}

// ---------------- flat rendezvous: 1-RMW arrive, direct group-counter poll ----
// arr layout: (set*8 + g) * 16 u32 (64B lines). Arrive: group fetch_add.
// Wait: thread g polls counter (set, g0+g) until >= 32*ep. __syncthreads
// before arrive drains each wave's data stores (compiler emits vmcnt(0)
// before s_barrier), so a counted arrival implies data is at MALL.
__device__ __forceinline__ void arrv(u32* arr, int set, u32 ep, int tid, int blk){
  __syncthreads();
  if (tid == 0){
    int g = (blk >> 5) & 7;
    __hip_atomic_fetch_add(&arr[(set * 8 + g) * 16], 1u, __ATOMIC_RELAXED, AGT);
  }
}
__device__ __forceinline__ void waitg(u32* arr, int set, int g0, int ng, u32 ep, int tid){
  if (tid < ng){
    const u32 tgt = 32u * ep;
    while (aload32(&arr[(set * 8 + g0 + tid) * 16]) < tgt) __builtin_amdgcn_s_sleep(2);
  }
  if (tid == 0) __builtin_amdgcn_sched_barrier(0);
  __syncthreads();
}

// ---------------- persistent scan kernel ----------------
struct CoopA {
  const us16 *wta, *wqt, *x2p, *kh, *kl;
  const float *mem, *vatt, *bperm;
  us16 *hpr;
  float *ucr, *sr, *qr, *cbuf, *hf32;
  u32 *arr;
};

__global__ void __launch_bounds__(512, 1) k_coop(CoopA a){
  __shared__ us16 khi[32][1024];
  __shared__ us16 klo[32][1024];
  __shared__ float zp[8][512];
  __shared__ float esc[16];

  __builtin_amdgcn_fence(__ATOMIC_ACQUIRE, "agent");

  const int tid = threadIdx.x, blk = blockIdx.x;
  const int wv = tid >> 6, lane = tid & 63;
  const int r0 = lane & 15, kg = lane >> 4;
  const int b16 = blk >> 4, s0c = (blk & 15) * 16;
  const int colbase = blk * 16;
  const int u0 = lane * 16;

  bf16x8 wr[8][3];
#pragma unroll
  for (int ks = 0; ks < 8; ++ks){
    const size_t wb = (size_t)(colbase + r0) * 2048 + (size_t)wv * 256 + ks * 32 + kg * 8;
#pragma unroll
    for (int p = 0; p < 3; ++p)
      wr[ks][p] = pin_reg(*(const bf16x8*)&a.wta[(size_t)p * WTPL + wb]);
  }

  {
    for (int i = tid; i < 4096; i += 512){
      int r = i >> 7, c8 = (i & 127) * 8;
      int gb = (r < 16) ? b16 : (16 + b16);
      int s  = s0c + (r & 15);
      const size_t kb = ((size_t)(gb * 256 + s)) * 1024 + c8;
      *(bf16x8*)&khi[r][c8] = *(const bf16x8*)&a.kh[kb];
      *(bf16x8*)&klo[r][c8] = *(const bf16x8*)&a.kl[kb];
    }
  }
  __syncthreads();

  auto phaseA = [&](int g, int t){
    const int gr = g * 16;
    f32x4 acc = (f32x4){0.f, 0.f, 0.f, 0.f};
    float rsv = (wv >= 6) ? 1.f / a.sr[(size_t)t * 32 + gr + r0] : 0.f;
#pragma unroll
    for (int ks = 0; ks < 8; ++ks){
      const int kf = wv * 256 + ks * 32 + kg * 8;
      bf16x8 w0 = wr[ks][0], w1 = wr[ks][1], w2 = wr[ks][2];
      bf16x8 a0, a1, a2;
      if (wv < 2){
        const size_t xb = ((size_t)(gr + r0) * 200 + t) * 512 + kf;
        a0 = *(const bf16x8*)&a.x2p[xb];
        a1 = *(const bf16x8*)&a.x2p[X2PL + xb];
        a2 = *(const bf16x8*)&a.x2p[2 * X2PL + xb];
      } else if (wv < 6){
        const int hk = kf - 512;
        const us16* hb = a.hpr + (size_t)t * 98304 + (size_t)(gr + r0) * 1024 + hk;
        a0 = ld16(hb); a1 = ld16(hb + 32768); a2 = ld16(hb + 65536);
      } else {
        const int ek = kf - 1536;
        const float* up = a.ucr + (size_t)t * 16384 + (size_t)(gr + r0) * 512 + ek;
        f32_frag3(up, rsv, a0, a1, a2);
      }
      acc = MFMA16(a0, w0, acc, 0,0,0); acc = MFMA16(a0, w1, acc, 0,0,0);
      acc = MFMA16(a1, w0, acc, 0,0,0); acc = MFMA16(a0, w2, acc, 0,0,0);
      acc = MFMA16(a1, w1, acc, 0,0,0); acc = MFMA16(a2, w0, acc, 0,0,0);
    }
#pragma unroll
    for (int i = 0; i < 4; ++i)
      zp[wv][(kg * 4 + i) * 16 + r0] = acc[i];
    __syncthreads();
    float z = 0.f;
    if (tid < 256){
#pragma unroll
      for (int w = 0; w < 8; ++w) z += zp[w][tid];
      z += a.bperm[colbase + (tid & 15)];
    }
    __syncthreads();
    if (tid < 256) zp[0][tid] = z;
    __syncthreads();
    if (tid < 64){
      int bl = tid >> 2, ul = tid & 3, u = blk * 4 + ul;
      int b = gr + bl;
      float zi = zp[0][bl * 16 + ul * 4 + 0];
      float zf = zp[0][bl * 16 + ul * 4 + 1];
      float zg = zp[0][bl * 16 + ul * 4 + 2];
      float zo = zp[0][bl * 16 + ul * 4 + 3];
      float co = a.cbuf[b * 1024 + u];
      float cn = sigf(zf) * co + sigf(zi) * tanh_fast(zg);
      float hn = sigf(zo) * tanh_fast(cn);
      a.cbuf[b * 1024 + u] = cn;
      a.hf32[b * 1024 + u] = hn;
      us16 s0, s1, s2; split3(hn, s0, s1, s2);
      us16* hb = a.hpr + (size_t)(t + 1) * 98304 + b * 1024 + u;
      astore16(hb, s0);
      astore16(hb + 32768, s1);
      astore16(hb + 65536, s2);
    }
  };

  auto phaseB = [&](int g, int t, int colb){
    const int gr = g * 16;
    f32x4 acc = (f32x4){0.f, 0.f, 0.f, 0.f};
#pragma unroll
    for (int ks = 0; ks < 4; ++ks){
      const int kf = wv * 128 + ks * 32 + kg * 8;
      const size_t wb = (size_t)(colb + r0) * 1024 + kf;
      bf16x8 w0 = *(const bf16x8*)&a.wqt[wb];
      bf16x8 w1 = *(const bf16x8*)&a.wqt[WQPL + wb];
      bf16x8 w2 = *(const bf16x8*)&a.wqt[2 * WQPL + wb];
      const us16* hb = a.hpr + (size_t)(t + 1) * 98304 + (size_t)(gr + r0) * 1024 + kf;
      bf16x8 a0 = ld16(hb), a1 = ld16(hb + 32768), a2 = ld16(hb + 65536);
      acc = MFMA16(a0, w0, acc, 0,0,0); acc = MFMA16(a0, w1, acc, 0,0,0);
      acc = MFMA16(a1, w0, acc, 0,0,0); acc = MFMA16(a0, w2, acc, 0,0,0);
      acc = MFMA16(a1, w1, acc, 0,0,0); acc = MFMA16(a2, w0, acc, 0,0,0);
    }
#pragma unroll
    for (int i = 0; i < 4; ++i)
      zp[wv][(kg * 4 + i) * 16 + r0] = acc[i];
    __syncthreads();
    if (tid < 256){
      float q = 0.f;
#pragma unroll
      for (int w = 0; w < 8; ++w) q += zp[w][tid];
      astoref(&a.qr[(size_t)t * 32768 + (size_t)(gr + (tid >> 4)) * 1024 + colb + (tid & 15)], q);
    }
  };

  auto phaseC = [&](int g, int t){
    const int b = g * 16 + b16;
    float qv[16], vv[16];
    {
      const float* qp = a.qr + (size_t)t * 32768 + (size_t)b * 1024 + u0;
      float4 q0 = *(const float4*)qp;
      float4 q1 = *(const float4*)(qp + 4);
      float4 q2 = *(const float4*)(qp + 8);
      float4 q3 = *(const float4*)(qp + 12);
      qv[0]=q0.x; qv[1]=q0.y; qv[2]=q0.z; qv[3]=q0.w;
      qv[4]=q1.x; qv[5]=q1.y; qv[6]=q1.z; qv[7]=q1.w;
      qv[8]=q2.x; qv[9]=q2.y; qv[10]=q2.z; qv[11]=q2.w;
      qv[12]=q3.x; qv[13]=q3.y; qv[14]=q3.z; qv[15]=q3.w;
      float4 v0 = *(const float4*)(a.vatt + u0);
      float4 v1 = *(const float4*)(a.vatt + u0 + 4);
      float4 v2 = *(const float4*)(a.vatt + u0 + 8);
      float4 v3 = *(const float4*)(a.vatt + u0 + 12);
      vv[0]=v0.x; vv[1]=v0.y; vv[2]=v0.z; vv[3]=v0.w;
      vv[4]=v1.x; vv[5]=v1.y; vv[6]=v1.z; vv[7]=v1.w;
      vv[8]=v2.x; vv[9]=v2.y; vv[10]=v2.z; vv[11]=v2.w;
      vv[12]=v3.x; vv[13]=v3.y; vv[14]=v3.z; vv[15]=v3.w;
    }
#pragma unroll
    for (int m = 0; m < 2; ++m){
      const int sl = wv * 2 + m;
      const int kr = g * 16 + sl;
      bf16x8 h0 = *(const bf16x8*)&khi[kr][u0];
      bf16x8 h1 = *(const bf16x8*)&khi[kr][u0 + 8];
      bf16x8 l0 = *(const bf16x8*)&klo[kr][u0];
      bf16x8 l1 = *(const bf16x8*)&klo[kr][u0 + 8];
      float part = 0.f;
#pragma unroll
      for (int j = 0; j < 8; ++j){
        float kva = h2f((us16)h0[j]) + h2f((us16)l0[j]);
        part += vv[j] * tanh_fast(kva + qv[j]);
        float kvb = h2f((us16)h1[j]) + h2f((us16)l1[j]);
        part += vv[8 + j] * tanh_fast(kvb + qv[8 + j]);
      }
#pragma unroll
      for (int off = 32; off; off >>= 1) part += __shfl_xor(part, off);
      if (lane == 0) esc[sl] = __expf(part);    // max-free softmax
    }
    __syncthreads();
    if (tid == 0){
      float bs = 0.f;
#pragma unroll
      for (int i = 0; i < 16; ++i) bs += esc[i];
      aaddf(&a.sr[(size_t)(t + 1) * 32 + b], bs);
    }
    {
      float ac0 = 0.f, ac1 = 0.f;
      const float* mrow = a.mem + ((size_t)(b * 256 + s0c)) * 512 + tid;
#pragma unroll
      for (int j = 0; j < 16; j += 2){
        ac0 += esc[j]     * mrow[(size_t)j * 512];
        ac1 += esc[j + 1] * mrow[(size_t)(j + 1) * 512];
      }
      aaddf(&a.ucr[(size_t)(t + 1) * 16384 + b * 512 + tid], ac0 + ac1);
    }
    __syncthreads();
  };

  for (int t = 0; t < 200; ++t){
    const u32 ep = (u32)(t + 1);
    waitg(a.arr, SC0, 0, 8, (u32)t, tid);
    phaseA(0, t);
    arrv(a.arr, SA0, ep, tid, blk);
    waitg(a.arr, SC1, 0, 8, (u32)t, tid);
    phaseA(1, t);
    arrv(a.arr, SA1, ep, tid, blk);
    if (blk < 64){
      waitg(a.arr, SA0, 0, 8, ep, tid);
      phaseB(0, t, blk * 16);
      arrv(a.arr, SB0, ep, tid, blk);
    } else if (blk < 128){
      waitg(a.arr, SA1, 0, 8, ep, tid);
      phaseB(1, t, (blk - 64) * 16);
      arrv(a.arr, SB1, ep, tid, blk);
    }
    waitg(a.arr, SB0, 0, 2, ep, tid);
    phaseC(0, t);
    arrv(a.arr, SC0, ep, tid, blk);
    waitg(a.arr, SB1, 2, 2, ep, tid);
    phaseC(1, t);
    arrv(a.arr, SC1, ep, tid, blk);
  }
}

__global__ void k_copy_hc(const float* __restrict__ h, const float* __restrict__ c,
                          float* __restrict__ out){
  int i = blockIdx.x * 256 + threadIdx.x;
  if (i < 32768){
    out[512000 + i] = h[i];
    out[544768 + i] = c[i];
  }
}

// ---------------------------------------------------------------------------
extern "C" void kernel_launch(void* const* d_in, const int* in_sizes, int n_in,
                              void* d_out, int out_size, void* d_ws, size_t ws_size,
                              hipStream_t stream){
  const float* inputs = (const float*)d_in[0];
  const float* memory = (const float*)d_in[1];
  const float* W1     = (const float*)d_in[2];
  const float* b1     = (const float*)d_in[3];
  const float* W2     = (const float*)d_in[4];
  const float* b2     = (const float*)d_in[5];
  const float* Wx     = (const float*)d_in[6];
  const float* Wh     = (const float*)d_in[7];
  const float* b_lstm = (const float*)d_in[8];
  const float* Wm     = (const float*)d_in[9];
  const float* Wq     = (const float*)d_in[10];
  const float* v_att  = (const float*)d_in[11];
  const float* Wa     = (const float*)d_in[12];
  const float* Wp     = (const float*)d_in[13];
  const float* bp     = (const float*)d_in[14];
  float* out = (float*)d_out;
  char* ws = (char*)d_ws;
  if (ws_size < TOTAL_WS) return;

  us16* WTA    = (us16*)(ws + OFF_WTA);
  us16* WQT    = (us16*)(ws + OFF_WQT);
  us16* X2P    = (us16*)(ws + OFF_X2P);
  us16* KEYH   = (us16*)(ws + OFF_KEYH);
  float* X1    = (float*)(ws + OFF_X1);
  us16* HPR    = (us16*)(ws + OFF_HPR);
  float* UCR   = (float*)(ws + OFF_UCR);
  float* SR    = (float*)(ws + OFF_SR);
  float* QR    = (float*)(ws + OFF_QR);
  float* CB    = (float*)(ws + OFF_CB);
  float* HF    = (float*)(ws + OFF_HF);
  us16* WAPN   = (us16*)(ws + OFF_WAPN);
  float* BPM   = (float*)(ws + OFF_BPERM);
  u32*  ARR    = (u32*)(ws + OFF_ARR);

  k_init<<<256, 256, 0, stream>>>((u32*)HPR, UCR, SR, CB, ARR, b_lstm, BPM);
  k_transp3<<<dim3(32, 32), 256, 0, stream>>>(Wq, WQT, 1024, 1024, 1024, (long long)WQPL, 0);
  k_transp3<<<dim3(128, 16), 256, 0, stream>>>(Wx, WTA, 512, 4096, 2048, (long long)WTPL, 1);

  // fold: WTA rows 512..2047 = [Wh + WaTop@Wxb ; WaBot@Wxb], gate-permuted, triple-split
  k_gemm3<3,1,1><<<dim3(12, 64), 256, 0, stream>>>(Wa, Wx + (size_t)512 * 4096, WTA,
                                                   1536, 4096, 1024, 3, Wh, 0);
  // WapN = Wa @ Wp  [1536][80] bf16
  k_gemm3<3,1,1><<<dim3(12, 2), 256, 0, stream>>>(Wa, Wp, WAPN, 1536, 80, 1024, 4, nullptr, 80);
  // prenet 1: x1 = relu(inputs @ W1 + b1)  f32
  k_gemm3<3,1,1><<<dim3(50, 16), 256, 0, stream>>>(inputs, W1, X1, 6400, 1024, 80, 0, b1, 1024);
  // prenet 2: x2 = relu(x1 @ W2 + b2) -> triple planes
  k_gemm3<3,1,1><<<dim3(50, 8), 256, 0, stream>>>(X1, W2, X2P, 6400, 512, 1024, 1, b2, 512);
  // keys = memory @ Wm -> fp16 pair (overwrites X1 alias region; X1 dead now)
  k_gemm3<3,1,1><<<dim3(64, 16), 256, 0, stream>>>(memory, Wm, KEYH, 8192, 1024, 512, 2, nullptr, 1024);

  CoopA ca;
  ca.wta = WTA; ca.wqt = WQT; ca.x2p = X2P; ca.kh = KEYH; ca.kl = KEYH + WTPL;
  ca.mem = memory; ca.vatt = v_att; ca.bperm = BPM;
  ca.hpr = HPR; ca.ucr = UCR; ca.sr = SR;
  ca.qr = QR; ca.cbuf = CB; ca.hf32 = HF; ca.arr = ARR;
  void* args[] = {(void*)&ca};
  hipLaunchCooperativeKernel((const void*)k_coop, dim3(256), dim3(512), args, 0, stream);

  // mel = hist[1..200] @ WapN + bp  (A staged from rolling buffers; ro=32)
  k_gemmE<0><<<dim3(50, 2), 256, 0, stream>>>(HPR, UCR, SR, WAPN, out,
                                              6400, 80, 1536, 5, bp, 0, 32);
  // attn = hist[200] @ Wa  (ro=6400)
  k_gemmE<1><<<dim3(1, 16), 256, 0, stream>>>(HPR, UCR, SR, Wa, out + 577536,
                                              32, 1024, 1536, 6, nullptr, 1024, 6400);
  k_copy_hc<<<128, 256, 0, stream>>>(HF, CB, out);
}

// Round 17
// 11479.222 us; speedup vs baseline: 1.0618x; 1.0618x over previous
//
#include <hip/hip_runtime.h>

// ---------------------------------------------------------------------------
// TacotronMelDecoder on MI355X (gfx950) — precision-hardened persistent scan.
// R17 = R15 (best: coop 9.02ms, total 11.69ms) + wider prologue GEMM tiles:
// k_gemm3 templated on NF (col-fragments); fold/keys/prenet2 use 128x128
// tiles (NF=8, 2x arithmetic intensity, same staging traffic). Bit-identical
// numerics (per-output K-order unchanged). Coop loop/barrier = R15 verbatim.
// ---------------------------------------------------------------------------

typedef unsigned short us16;
typedef unsigned int u32;
typedef unsigned long long u64;
typedef __attribute__((ext_vector_type(8))) short bf16x8;
typedef __attribute__((ext_vector_type(4))) float f32x4;

#define MFMA16 __builtin_amdgcn_mfma_f32_16x16x32_bf16
#define AGT __HIP_MEMORY_SCOPE_AGENT

__device__ __forceinline__ us16 f2bf(float f){
  u32 u = __builtin_bit_cast(u32, f);
  u += 0x7fffu + ((u >> 16) & 1u);
  return (us16)(u >> 16);
}
__device__ __forceinline__ float bf2f(us16 h){
  return __builtin_bit_cast(float, ((u32)h) << 16);
}
__device__ __forceinline__ float h2f(us16 u){
  _Float16 h = __builtin_bit_cast(_Float16, u); return (float)h;
}
__device__ __forceinline__ us16 f2h(float f){
  _Float16 h = (_Float16)f; return __builtin_bit_cast(us16, h);
}
__device__ __forceinline__ void split3(float v, us16& s0, us16& s1, us16& s2){
  s0 = f2bf(v); float r = v - bf2f(s0);
  s1 = f2bf(r); r -= bf2f(s1);
  s2 = f2bf(r);
}
__device__ __forceinline__ float tanh_fast(float x){
  float e = __expf(-2.f * fmaxf(x, -40.f));
  return (1.f - e) / (1.f + e);
}
__device__ __forceinline__ float sigf(float x){
  return 1.f / (1.f + __expf(-x));
}

__device__ __forceinline__ u32 aload32(const u32* p){
  return __hip_atomic_load(p, __ATOMIC_RELAXED, AGT);
}
__device__ __forceinline__ void astore16(us16* p, us16 v){
  __hip_atomic_store(p, v, __ATOMIC_RELAXED, AGT);
}
__device__ __forceinline__ void astoref(float* p, float v){
  __hip_atomic_store(p, v, __ATOMIC_RELAXED, AGT);
}
__device__ __forceinline__ void sigflag(u32* p, u32 v){
  __hip_atomic_store(p, v, __ATOMIC_RELAXED, AGT);
}
__device__ __forceinline__ void aaddf(float* p, float v){
  __hip_atomic_fetch_add(p, v, __ATOMIC_RELAXED, AGT);
}
__device__ __forceinline__ bf16x8 ld16(const us16* p){
  return *(const bf16x8*)p;
}
// opacity: keep a loaded fragment in regs (non-rematerializable)
__device__ __forceinline__ bf16x8 pin_reg(bf16x8 v){
  f32x4 t = __builtin_bit_cast(f32x4, v);
  asm volatile("" : "+v"(t));
  return __builtin_bit_cast(bf16x8, t);
}
// 8 cached fp32 -> scaled triple-split bf16 fragments (ctx path)
__device__ __forceinline__ void f32_frag3(const float* p, float rs,
                                          bf16x8& f0, bf16x8& f1, bf16x8& f2){
  float4 t0 = *(const float4*)p;
  float4 t1 = *(const float4*)(p + 4);
  float tf[8] = {t0.x, t0.y, t0.z, t0.w, t1.x, t1.y, t1.z, t1.w};
#pragma unroll
  for (int i = 0; i < 8; ++i){
    float v = tf[i] * rs;
    us16 s0, s1, s2; split3(v, s0, s1, s2);
    f0[i] = (short)s0; f1[i] = (short)s1; f2[i] = (short)s2;
  }
}

// ---------------- workspace layout (bytes) ----------------
#define OFF_WTA    0ull            // 3 planes [4096][2048] bf16 (cols permuted u*4+gate)
#define OFF_WQT    50331648ull     // 3 planes [1024][1024] bf16 (Wq^T)
#define OFF_X2P    56623104ull     // 3 planes [32*200][512] bf16 (prenet out)
#define OFF_KEYH   76283904ull     // [8192][1024] fp16 hi
#define OFF_KEYL   93061120ull     // [8192][1024] fp16 lo
#define OFF_X1     76283904ull     // alias over KEYH/KEYL (dead before keys written)
#define OFF_HPR    129597440ull    // [201][3][32][1024] bf16 h planes (rolling)
#define OFF_UCR    169115648ull    // [201][32][512] f32 raw ctx sums (rolling, atomics)
#define OFF_SR     182288384ull    // [201][32] f32 softmax sums (rolling; slot0=1)
#define OFF_CB     182314112ull    // [32][1024] f32 c state (block-private)
#define OFF_HF     182445184ull    // [32][1024] f32 final h (plain)
#define OFF_WAPN   182576256ull    // [1536][80] bf16 (Wa@Wp natural)
#define OFF_BPERM  182822016ull    // [4096] f32
#define OFF_ARR    182838400ull    // sync: 6 sets x 8 grp cnt + roots + releases
#define OFF_QR     182870016ull    // [200][32][1024] f32 q (rolling)
#define TOTAL_WS   209094656ull

#define WTPL 8388608ull
#define WQPL 1048576ull
#define X2PL 3276800ull

// sync sets
#define SA0 0
#define SA1 1
#define SB0 2
#define SB1 3
#define SC0 4
#define SC1 5

// ---------------- init + bperm (merged; re-run every launch: replay-safe) ----
__global__ void k_init(u32* hpr0, float* ucr, float* sr, float* cbuf, u32* arr,
                       const float* __restrict__ bl, float* __restrict__ bpm){
  u32 id = blockIdx.x * 256u + threadIdx.x;
  const u32 gs = 65536u;
  for (u32 i = id; i < 49152u;   i += gs) hpr0[i] = 0u;     // hp slot 0 (3 planes)
  for (u32 i = id; i < 3293184u; i += gs) ucr[i]  = 0.f;
  for (u32 i = id; i < 6432u;    i += gs) sr[i]   = (i < 32u) ? 1.f : 0.f;
  for (u32 i = id; i < 32768u;   i += gs) cbuf[i] = 0.f;
  for (u32 i = id; i < 2048u;    i += gs) arr[i]  = 0u;
  if (id < 4096u) bpm[((id & 1023u) << 2) | (id >> 10)] = bl[id];
}

// ---------------- transpose f32 -> 3 bf16 planes (+optional gate perm) ----------------
__global__ void k_transp3(const float* __restrict__ src, us16* __restrict__ dst,
                          int srows, int scols, int ldd, long long pstride, int perm){
  __shared__ float tile[32][33];
  int bx = blockIdx.x * 32, by = blockIdx.y * 32;
  int tx = threadIdx.x & 31, ty = threadIdx.x >> 5;
#pragma unroll
  for (int i = 0; i < 4; ++i){
    int r = by + ty + i * 8, c = bx + tx;
    tile[ty + i * 8][tx] = (r < srows && c < scols) ? src[(size_t)r * scols + c] : 0.f;
  }
  __syncthreads();
#pragma unroll
  for (int i = 0; i < 4; ++i){
    int c = bx + ty + i * 8;
    int r = by + tx;
    if (c < scols && r < srows){
      int oc = perm ? (((c & 1023) << 2) | (c >> 10)) : c;
      float v = tile[tx][ty + i * 8];
      us16 s0, s1, s2; split3(v, s0, s1, s2);
      size_t base = (size_t)oc * ldd + r;
      dst[base] = s0; dst[(size_t)pstride + base] = s1; dst[2ull * pstride + base] = s2;
    }
  }
}

// ---------------- generic triple-split GEMM: C[M,N] = A[M,K] @ B[K,N] ----------------
// NF = column fragments (tile N = NF*16). AF/BF: 0 bf16 | 1 f32 split-on-fly.
// modes: 0 f32+bias+relu | 1 relu -> x2 triple planes | 2 keys fp16 pair
//        3 fold -> WTA planes (+Wh, perm) | 4 bf16 plain
template<int NP, int AF, int BF, int NF>
__global__ void __launch_bounds__(256)
k_gemm3(const void* __restrict__ Ap, const void* __restrict__ Bp, void* __restrict__ outp,
        int M, int N, int K, int mode, const float* __restrict__ aux, int ldd){
  constexpr int BN = NF * 16;
  __shared__ us16 At[NP][128][72];
  __shared__ us16 Bt[NP][BN][72];
  const int tid = threadIdx.x, wv = tid >> 6, lane = tid & 63;
  const int r0 = lane & 15, kg = lane >> 4;
  const int rb = blockIdx.x * 128, cb = blockIdx.y * BN;
  f32x4 acc[2][NF];
#pragma unroll
  for (int a = 0; a < 2; ++a)
#pragma unroll
    for (int b = 0; b < NF; ++b) acc[a][b] = (f32x4){0.f, 0.f, 0.f, 0.f};

  const int nkt = (K + 63) >> 6;
  for (int kt = 0; kt < nkt; ++kt){
    const int kb = kt * 64;
    for (int e = tid; e < 8192; e += 256){
      int r = e >> 6, k = e & 63, ga = rb + r, gk = kb + k;
      bool ok = (ga < M) && (gk < K);
      if constexpr (AF == 1){
        float v = ok ? ((const float*)Ap)[(size_t)ga * K + gk] : 0.f;
        us16 s0, s1, s2; split3(v, s0, s1, s2);
        At[0][r][k] = s0;
        if constexpr (NP == 3){ At[1][r][k] = s1; At[2][r][k] = s2; }
      } else {
        At[0][r][k] = ok ? ((const us16*)Ap)[(size_t)ga * K + gk] : (us16)0;
      }
    }
    for (int e = tid; e < 64 * BN; e += 256){
      int kr = e / BN, c = e % BN, gk = kb + kr, gc = cb + c;
      bool ok = (gk < K) && (gc < N);
      if constexpr (BF == 1){
        float v = ok ? ((const float*)Bp)[(size_t)gk * N + gc] : 0.f;
        us16 s0, s1, s2; split3(v, s0, s1, s2);
        Bt[0][c][kr] = s0;
        if constexpr (NP == 3){ Bt[1][c][kr] = s1; Bt[2][c][kr] = s2; }
      } else {
        Bt[0][c][kr] = ok ? ((const us16*)Bp)[(size_t)gk * N + gc] : (us16)0;
      }
    }
    __syncthreads();
#pragma unroll
    for (int kk = 0; kk < 64; kk += 32){
      bf16x8 af[NP][2];
#pragma unroll
      for (int p = 0; p < NP; ++p){
        af[p][0] = *(const bf16x8*)&At[p][wv * 32 + r0][kk + kg * 8];
        af[p][1] = *(const bf16x8*)&At[p][wv * 32 + 16 + r0][kk + kg * 8];
      }
#pragma unroll
      for (int cf = 0; cf < NF; ++cf){
        bf16x8 bv[NP];
#pragma unroll
        for (int p = 0; p < NP; ++p) bv[p] = *(const bf16x8*)&Bt[p][cf * 16 + r0][kk + kg * 8];
#pragma unroll
        for (int rf = 0; rf < 2; ++rf){
          acc[rf][cf] = MFMA16(af[0][rf], bv[0], acc[rf][cf], 0, 0, 0);
          if constexpr (NP == 3){
            acc[rf][cf] = MFMA16(af[0][rf], bv[1], acc[rf][cf], 0, 0, 0);
            acc[rf][cf] = MFMA16(af[1][rf], bv[0], acc[rf][cf], 0, 0, 0);
            acc[rf][cf] = MFMA16(af[0][rf], bv[2], acc[rf][cf], 0, 0, 0);
            acc[rf][cf] = MFMA16(af[1][rf], bv[1], acc[rf][cf], 0, 0, 0);
            acc[rf][cf] = MFMA16(af[2][rf], bv[0], acc[rf][cf], 0, 0, 0);
          }
        }
      }
    }
    __syncthreads();
  }
  us16* o16 = (us16*)outp; float* of = (float*)outp;
#pragma unroll
  for (int rf = 0; rf < 2; ++rf)
#pragma unroll
    for (int cf = 0; cf < NF; ++cf)
#pragma unroll
      for (int i = 0; i < 4; ++i){
        int r = rb + wv * 32 + rf * 16 + kg * 4 + i;
        int c = cb + cf * 16 + r0;
        if (r >= M || c >= N) continue;
        float v = acc[rf][cf][i];
        if (mode == 0){
          of[(size_t)r * ldd + c] = fmaxf(v + aux[c], 0.f);
        } else if (mode == 1){
          v = fmaxf(v + aux[c], 0.f);
          us16 s0, s1, s2; split3(v, s0, s1, s2);
          size_t b2 = (size_t)r * ldd + c;
          o16[b2] = s0; o16[X2PL + b2] = s1; o16[2 * X2PL + b2] = s2;
        } else if (mode == 2){
          us16 hh = f2h(v); float rem = v - h2f(hh); us16 hl = f2h(rem);
          size_t b2 = (size_t)r * 1024 + c;
          o16[b2] = hh; o16[WTPL + b2] = hl;
        } else if (mode == 3){
          float w = v + (r < 1024 ? aux[(size_t)r * 4096 + c] : 0.f);
          int pc = (c & 1023) * 4 + (c >> 10);
          us16 s0, s1, s2; split3(w, s0, s1, s2);
          size_t b2 = (size_t)pc * 2048 + 512 + r;
          o16[b2] = s0; o16[WTPL + b2] = s1; o16[2 * WTPL + b2] = s2;
        } else {
          o16[(size_t)r * ldd + c] = f2bf(v);
        }
      }
}

// ---------------- epilogue GEMM: A staged from rolling state buffers ----------
template<int BF>
__global__ void __launch_bounds__(256)
k_gemmE(const us16* __restrict__ hpr, const float* __restrict__ ucr,
        const float* __restrict__ sr, const void* __restrict__ Bp,
        float* __restrict__ of, int M, int N, int K, int mode,
        const float* __restrict__ aux, int ldd, int ro){
  __shared__ us16 At[128][72];
  __shared__ us16 Bt[64][72];
  const int tid = threadIdx.x, wv = tid >> 6, lane = tid & 63;
  const int r0 = lane & 15, kg = lane >> 4;
  const int rb = blockIdx.x * 128, cb = blockIdx.y * 64;
  f32x4 acc[2][4];
#pragma unroll
  for (int a = 0; a < 2; ++a)
#pragma unroll
    for (int b = 0; b < 4; ++b) acc[a][b] = (f32x4){0.f, 0.f, 0.f, 0.f};

  const int nkt = (K + 63) >> 6;
  for (int kt = 0; kt < nkt; ++kt){
    const int kb = kt * 64;
    for (int e = tid; e < 8192; e += 256){
      int r = e >> 6, k = e & 63, ga = rb + r, gk = kb + k;
      us16 v = 0;
      if (ga < M && gk < K){
        int row = ro + ga, t = row >> 5, b = row & 31;
        if (gk < 1024){
          v = hpr[(size_t)t * 98304 + b * 1024 + gk];
        } else {
          float rs = 1.f / sr[(size_t)t * 32 + b];
          v = f2bf(ucr[(size_t)t * 16384 + b * 512 + (gk - 1024)] * rs);
        }
      }
      At[r][k] = v;
    }
    for (int e = tid; e < 4096; e += 256){
      int kr = e >> 6, c = e & 63, gk = kb + kr, gc = cb + c;
      bool ok = (gk < K) && (gc < N);
      if constexpr (BF == 1){
        float v = ok ? ((const float*)Bp)[(size_t)gk * N + gc] : 0.f;
        Bt[c][kr] = f2bf(v);
      } else {
        Bt[c][kr] = ok ? ((const us16*)Bp)[(size_t)gk * N + gc] : (us16)0;
      }
    }
    __syncthreads();
#pragma unroll
    for (int kk = 0; kk < 64; kk += 32){
      bf16x8 a0 = *(const bf16x8*)&At[wv * 32 + r0][kk + kg * 8];
      bf16x8 a1 = *(const bf16x8*)&At[wv * 32 + 16 + r0][kk + kg * 8];
#pragma unroll
      for (int cf = 0; cf < 4; ++cf){
        bf16x8 bv = *(const bf16x8*)&Bt[cf * 16 + r0][kk + kg * 8];
        acc[0][cf] = MFMA16(a0, bv, acc[0][cf], 0, 0, 0);
        acc[1][cf] = MFMA16(a1, bv, acc[1][cf], 0, 0, 0);
      }
    }
    __syncthreads();
  }
#pragma unroll
  for (int rf = 0; rf < 2; ++rf)
#pragma unroll
    for (int cf = 0; cf < 4; ++cf)
#pragma unroll
      for (int i = 0; i < 4; ++i){
        int r = rb + wv * 32 + rf * 16 + kg * 4 + i;
        int c = cb + cf * 16 + r0;
        if (r >= M || c >= N) continue;
        float v = acc[rf][cf][i];
        if (mode == 5){
          of[((size_t)(r & 31) * 200 + (r >> 5)) * 80 + c] = v + aux[c];
        } else {
          of[(size_t)r * ldd + c] = v;
        }
      }
}

// ---------------- split arrive / wait (two-level, last-arriver-releases) ----
__device__ __forceinline__ void arrv(u32* arr, int set, u32 ng, u32 ep, int tid, int blk){
  __syncthreads();
  if (tid == 0){
    int g = (blk >> 5) & 7;
    u32 old = __hip_atomic_fetch_add(&arr[(set * 8 + g) * 32], 1u, __ATOMIC_RELAXED, AGT);
    if (old == 32u * ep - 1u){
      u32 r = __hip_atomic_fetch_add(&arr[(48 + set) * 32], 1u, __ATOMIC_RELAXED, AGT);
      if (r == ng * ep - 1u)
        sigflag(&arr[(56 + set) * 32], ep);
    }
  }
}
__device__ __forceinline__ void waitrel(u32* arr, int set, u32 ep, int tid){
  if (tid == 0){
    while (aload32(&arr[(56 + set) * 32]) < ep) __builtin_amdgcn_s_sleep(2);
    __builtin_amdgcn_sched_barrier(0);
  }
  __syncthreads();
}

// ---------------- persistent scan kernel (identical to R15) ----------------
struct CoopA {
  const us16 *wta, *wqt, *x2p, *kh, *kl;
  const float *mem, *vatt, *bperm;
  us16 *hpr;
  float *ucr, *sr, *qr, *cbuf, *hf32;
  u32 *arr;
};

__global__ void __launch_bounds__(512, 1) k_coop(CoopA a){
  __shared__ us16 khi[32][1024];
  __shared__ us16 klo[32][1024];
  __shared__ float zp[8][512];
  __shared__ float esc[16];

  __builtin_amdgcn_fence(__ATOMIC_ACQUIRE, "agent");

  const int tid = threadIdx.x, blk = blockIdx.x;
  const int wv = tid >> 6, lane = tid & 63;
  const int r0 = lane & 15, kg = lane >> 4;
  const int b16 = blk >> 4, s0c = (blk & 15) * 16;
  const int colbase = blk * 16;
  const int u0 = lane * 16;

  bf16x8 wr[8][3];
#pragma unroll
  for (int ks = 0; ks < 8; ++ks){
    const size_t wb = (size_t)(colbase + r0) * 2048 + (size_t)wv * 256 + ks * 32 + kg * 8;
#pragma unroll
    for (int p = 0; p < 3; ++p)
      wr[ks][p] = pin_reg(*(const bf16x8*)&a.wta[(size_t)p * WTPL + wb]);
  }

  {
    for (int i = tid; i < 4096; i += 512){
      int r = i >> 7, c8 = (i & 127) * 8;
      int gb = (r < 16) ? b16 : (16 + b16);
      int s  = s0c + (r & 15);
      const size_t kb = ((size_t)(gb * 256 + s)) * 1024 + c8;
      *(bf16x8*)&khi[r][c8] = *(const bf16x8*)&a.kh[kb];
      *(bf16x8*)&klo[r][c8] = *(const bf16x8*)&a.kl[kb];
    }
  }
  __syncthreads();

  auto phaseA = [&](int g, int t){
    const int gr = g * 16;
    f32x4 acc = (f32x4){0.f, 0.f, 0.f, 0.f};
    float rsv = (wv >= 6) ? 1.f / a.sr[(size_t)t * 32 + gr + r0] : 0.f;
#pragma unroll
    for (int ks = 0; ks < 8; ++ks){
      const int kf = wv * 256 + ks * 32 + kg * 8;
      bf16x8 w0 = wr[ks][0], w1 = wr[ks][1], w2 = wr[ks][2];
      bf16x8 a0, a1, a2;
      if (wv < 2){
        const size_t xb = ((size_t)(gr + r0) * 200 + t) * 512 + kf;
        a0 = *(const bf16x8*)&a.x2p[xb];
        a1 = *(const bf16x8*)&a.x2p[X2PL + xb];
        a2 = *(const bf16x8*)&a.x2p[2 * X2PL + xb];
      } else if (wv < 6){
        const int hk = kf - 512;
        const us16* hb = a.hpr + (size_t)t * 98304 + (size_t)(gr + r0) * 1024 + hk;
        a0 = ld16(hb); a1 = ld16(hb + 32768); a2 = ld16(hb + 65536);
      } else {
        const int ek = kf - 1536;
        const float* up = a.ucr + (size_t)t * 16384 + (size_t)(gr + r0) * 512 + ek;
        f32_frag3(up, rsv, a0, a1, a2);
      }
      acc = MFMA16(a0, w0, acc, 0,0,0); acc = MFMA16(a0, w1, acc, 0,0,0);
      acc = MFMA16(a1, w0, acc, 0,0,0); acc = MFMA16(a0, w2, acc, 0,0,0);
      acc = MFMA16(a1, w1, acc, 0,0,0); acc = MFMA16(a2, w0, acc, 0,0,0);
    }
#pragma unroll
    for (int i = 0; i < 4; ++i)
      zp[wv][(kg * 4 + i) * 16 + r0] = acc[i];
    __syncthreads();
    float z = 0.f;
    if (tid < 256){
#pragma unroll
      for (int w = 0; w < 8; ++w) z += zp[w][tid];
      z += a.bperm[colbase + (tid & 15)];
    }
    __syncthreads();
    if (tid < 256) zp[0][tid] = z;
    __syncthreads();
    if (tid < 64){
      int bl = tid >> 2, ul = tid & 3, u = blk * 4 + ul;
      int b = gr + bl;
      float zi = zp[0][bl * 16 + ul * 4 + 0];
      float zf = zp[0][bl * 16 + ul * 4 + 1];
      float zg = zp[0][bl * 16 + ul * 4 + 2];
      float zo = zp[0][bl * 16 + ul * 4 + 3];
      float co = a.cbuf[b * 1024 + u];
      float cn = sigf(zf) * co + sigf(zi) * tanh_fast(zg);
      float hn = sigf(zo) * tanh_fast(cn);
      a.cbuf[b * 1024 + u] = cn;
      a.hf32[b * 1024 + u] = hn;
      us16 s0, s1, s2; split3(hn, s0, s1, s2);
      us16* hb = a.hpr + (size_t)(t + 1) * 98304 + b * 1024 + u;
      astore16(hb, s0);
      astore16(hb + 32768, s1);
      astore16(hb + 65536, s2);
    }
  };

  auto phaseB = [&](int g, int t, int colb){
    const int gr = g * 16;
    f32x4 acc = (f32x4){0.f, 0.f, 0.f, 0.f};
#pragma unroll
    for (int ks = 0; ks < 4; ++ks){
      const int kf = wv * 128 + ks * 32 + kg * 8;
      const size_t wb = (size_t)(colb + r0) * 1024 + kf;
      bf16x8 w0 = *(const bf16x8*)&a.wqt[wb];
      bf16x8 w1 = *(const bf16x8*)&a.wqt[WQPL + wb];
      bf16x8 w2 = *(const bf16x8*)&a.wqt[2 * WQPL + wb];
      const us16* hb = a.hpr + (size_t)(t + 1) * 98304 + (size_t)(gr + r0) * 1024 + kf;
      bf16x8 a0 = ld16(hb), a1 = ld16(hb + 32768), a2 = ld16(hb + 65536);
      acc = MFMA16(a0, w0, acc, 0,0,0); acc = MFMA16(a0, w1, acc, 0,0,0);
      acc = MFMA16(a1, w0, acc, 0,0,0); acc = MFMA16(a0, w2, acc, 0,0,0);
      acc = MFMA16(a1, w1, acc, 0,0,0); acc = MFMA16(a2, w0, acc, 0,0,0);
    }
#pragma unroll
    for (int i = 0; i < 4; ++i)
      zp[wv][(kg * 4 + i) * 16 + r0] = acc[i];
    __syncthreads();
    if (tid < 256){
      float q = 0.f;
#pragma unroll
      for (int w = 0; w < 8; ++w) q += zp[w][tid];
      astoref(&a.qr[(size_t)t * 32768 + (size_t)(gr + (tid >> 4)) * 1024 + colb + (tid & 15)], q);
    }
  };

  auto phaseC = [&](int g, int t){
    const int b = g * 16 + b16;
    float qv[16], vv[16];
    {
      const float* qp = a.qr + (size_t)t * 32768 + (size_t)b * 1024 + u0;
      float4 q0 = *(const float4*)qp;
      float4 q1 = *(const float4*)(qp + 4);
      float4 q2 = *(const float4*)(qp + 8);
      float4 q3 = *(const float4*)(qp + 12);
      qv[0]=q0.x; qv[1]=q0.y; qv[2]=q0.z; qv[3]=q0.w;
      qv[4]=q1.x; qv[5]=q1.y; qv[6]=q1.z; qv[7]=q1.w;
      qv[8]=q2.x; qv[9]=q2.y; qv[10]=q2.z; qv[11]=q2.w;
      qv[12]=q3.x; qv[13]=q3.y; qv[14]=q3.z; qv[15]=q3.w;
      float4 v0 = *(const float4*)(a.vatt + u0);
      float4 v1 = *(const float4*)(a.vatt + u0 + 4);
      float4 v2 = *(const float4*)(a.vatt + u0 + 8);
      float4 v3 = *(const float4*)(a.vatt + u0 + 12);
      vv[0]=v0.x; vv[1]=v0.y; vv[2]=v0.z; vv[3]=v0.w;
      vv[4]=v1.x; vv[5]=v1.y; vv[6]=v1.z; vv[7]=v1.w;
      vv[8]=v2.x; vv[9]=v2.y; vv[10]=v2.z; vv[11]=v2.w;
      vv[12]=v3.x; vv[13]=v3.y; vv[14]=v3.z; vv[15]=v3.w;
    }
#pragma unroll
    for (int m = 0; m < 2; ++m){
      const int sl = wv * 2 + m;
      const int kr = g * 16 + sl;
      bf16x8 h0 = *(const bf16x8*)&khi[kr][u0];
      bf16x8 h1 = *(const bf16x8*)&khi[kr][u0 + 8];
      bf16x8 l0 = *(const bf16x8*)&klo[kr][u0];
      bf16x8 l1 = *(const bf16x8*)&klo[kr][u0 + 8];
      float part = 0.f;
#pragma unroll
      for (int j = 0; j < 8; ++j){
        float kva = h2f((us16)h0[j]) + h2f((us16)l0[j]);
        part += vv[j] * tanh_fast(kva + qv[j]);
        float kvb = h2f((us16)h1[j]) + h2f((us16)l1[j]);
        part += vv[8 + j] * tanh_fast(kvb + qv[8 + j]);
      }
#pragma unroll
      for (int off = 32; off; off >>= 1) part += __shfl_xor(part, off);
      if (lane == 0) esc[sl] = __expf(part);    // max-free softmax
    }
    __syncthreads();
    if (tid == 0){
      float bs = 0.f;
#pragma unroll
      for (int i = 0; i < 16; ++i) bs += esc[i];
      aaddf(&a.sr[(size_t)(t + 1) * 32 + b], bs);
    }
    {
      float ac0 = 0.f, ac1 = 0.f;
      const float* mrow = a.mem + ((size_t)(b * 256 + s0c)) * 512 + tid;
#pragma unroll
      for (int j = 0; j < 16; j += 2){
        ac0 += esc[j]     * mrow[(size_t)j * 512];
        ac1 += esc[j + 1] * mrow[(size_t)(j + 1) * 512];
      }
      aaddf(&a.ucr[(size_t)(t + 1) * 16384 + b * 512 + tid], ac0 + ac1);
    }
    __syncthreads();
  };

  for (int t = 0; t < 200; ++t){
    const u32 ep = (u32)(t + 1);
    waitrel(a.arr, SC0, (u32)t, tid);
    phaseA(0, t);
    arrv(a.arr, SA0, 8, ep, tid, blk);
    waitrel(a.arr, SC1, (u32)t, tid);
    phaseA(1, t);
    arrv(a.arr, SA1, 8, ep, tid, blk);
    if (blk < 64){
      waitrel(a.arr, SA0, ep, tid);
      phaseB(0, t, blk * 16);
      arrv(a.arr, SB0, 2, ep, tid, blk);
    } else if (blk < 128){
      waitrel(a.arr, SA1, ep, tid);
      phaseB(1, t, (blk - 64) * 16);
      arrv(a.arr, SB1, 2, ep, tid, blk);
    }
    waitrel(a.arr, SB0, ep, tid);
    phaseC(0, t);
    arrv(a.arr, SC0, 8, ep, tid, blk);
    waitrel(a.arr, SB1, ep, tid);
    phaseC(1, t);
    arrv(a.arr, SC1, 8, ep, tid, blk);
  }
}

__global__ void k_copy_hc(const float* __restrict__ h, const float* __restrict__ c,
                          float* __restrict__ out){
  int i = blockIdx.x * 256 + threadIdx.x;
  if (i < 32768){
    out[512000 + i] = h[i];
    out[544768 + i] = c[i];
  }
}

// ---------------------------------------------------------------------------
extern "C" void kernel_launch(void* const* d_in, const int* in_sizes, int n_in,
                              void* d_out, int out_size, void* d_ws, size_t ws_size,
                              hipStream_t stream){
  const float* inputs = (const float*)d_in[0];
  const float* memory = (const float*)d_in[1];
  const float* W1     = (const float*)d_in[2];
  const float* b1     = (const float*)d_in[3];
  const float* W2     = (const float*)d_in[4];
  const float* b2     = (const float*)d_in[5];
  const float* Wx     = (const float*)d_in[6];
  const float* Wh     = (const float*)d_in[7];
  const float* b_lstm = (const float*)d_in[8];
  const float* Wm     = (const float*)d_in[9];
  const float* Wq     = (const float*)d_in[10];
  const float* v_att  = (const float*)d_in[11];
  const float* Wa     = (const float*)d_in[12];
  const float* Wp     = (const float*)d_in[13];
  const float* bp     = (const float*)d_in[14];
  float* out = (float*)d_out;
  char* ws = (char*)d_ws;
  if (ws_size < TOTAL_WS) return;

  us16* WTA    = (us16*)(ws + OFF_WTA);
  us16* WQT    = (us16*)(ws + OFF_WQT);
  us16* X2P    = (us16*)(ws + OFF_X2P);
  us16* KEYH   = (us16*)(ws + OFF_KEYH);
  float* X1    = (float*)(ws + OFF_X1);
  us16* HPR    = (us16*)(ws + OFF_HPR);
  float* UCR   = (float*)(ws + OFF_UCR);
  float* SR    = (float*)(ws + OFF_SR);
  float* QR    = (float*)(ws + OFF_QR);
  float* CB    = (float*)(ws + OFF_CB);
  float* HF    = (float*)(ws + OFF_HF);
  us16* WAPN   = (us16*)(ws + OFF_WAPN);
  float* BPM   = (float*)(ws + OFF_BPERM);
  u32*  ARR    = (u32*)(ws + OFF_ARR);

  k_init<<<256, 256, 0, stream>>>((u32*)HPR, UCR, SR, CB, ARR, b_lstm, BPM);
  k_transp3<<<dim3(32, 32), 256, 0, stream>>>(Wq, WQT, 1024, 1024, 1024, (long long)WQPL, 0);
  k_transp3<<<dim3(128, 16), 256, 0, stream>>>(Wx, WTA, 512, 4096, 2048, (long long)WTPL, 1);

  // fold: WTA rows 512..2047 = [Wh + WaTop@Wxb ; WaBot@Wxb] — 128x128 tiles
  k_gemm3<3,1,1,8><<<dim3(12, 32), 256, 0, stream>>>(Wa, Wx + (size_t)512 * 4096, WTA,
                                                     1536, 4096, 1024, 3, Wh, 0);
  // WapN = Wa @ Wp  [1536][80] bf16
  k_gemm3<3,1,1,4><<<dim3(12, 2), 256, 0, stream>>>(Wa, Wp, WAPN, 1536, 80, 1024, 4, nullptr, 80);
  // prenet 1: x1 = relu(inputs @ W1 + b1)  f32
  k_gemm3<3,1,1,4><<<dim3(50, 16), 256, 0, stream>>>(inputs, W1, X1, 6400, 1024, 80, 0, b1, 1024);
  // prenet 2: x2 = relu(x1 @ W2 + b2) -> triple planes — 128x128 tiles
  k_gemm3<3,1,1,8><<<dim3(50, 4), 256, 0, stream>>>(X1, W2, X2P, 6400, 512, 1024, 1, b2, 512);
  // keys = memory @ Wm -> fp16 pair — 128x128 tiles (X1 dead now)
  k_gemm3<3,1,1,8><<<dim3(64, 8), 256, 0, stream>>>(memory, Wm, KEYH, 8192, 1024, 512, 2, nullptr, 1024);

  CoopA ca;
  ca.wta = WTA; ca.wqt = WQT; ca.x2p = X2P; ca.kh = KEYH; ca.kl = KEYH + WTPL;
  ca.mem = memory; ca.vatt = v_att; ca.bperm = BPM;
  ca.hpr = HPR; ca.ucr = UCR; ca.sr = SR;
  ca.qr = QR; ca.cbuf = CB; ca.hf32 = HF; ca.arr = ARR;
  void* args[] = {(void*)&ca};
  hipLaunchCooperativeKernel((const void*)k_coop, dim3(256), dim3(512), args, 0, stream);

  // mel = hist[1..200] @ WapN + bp  (A staged from rolling buffers; ro=32)
  k_gemmE<0><<<dim3(50, 2), 256, 0, stream>>>(HPR, UCR, SR, WAPN, out,
                                              6400, 80, 1536, 5, bp, 0, 32);
  // attn = hist[200] @ Wa  (ro=6400)
  k_gemmE<1><<<dim3(1, 16), 256, 0, stream>>>(HPR, UCR, SR, Wa, out + 577536,
                                              32, 1024, 1536, 6, nullptr, 1024, 6400);
  k_copy_hc<<<128, 256, 0, stream>>>(HF, CB, out);
}

// Round 18
// 10585.990 us; speedup vs baseline: 1.1514x; 1.0844x over previous
//
#include <hip/hip_runtime.h>

// ---------------------------------------------------------------------------
// TacotronMelDecoder on MI355X (gfx950) — precision-hardened persistent scan.
// R18 = R17 coop loop (best: 8.98ms) + FUSED prologue/epilogue:
// k_mega runs fold ∥ WapN ∥ prenet1 ∥ keys ∥ WQT-transp ∥ WTA-transp ∥ init
// concurrently (block-range dispatch, one <3,1,1,8> GEMM body, 110KB smem);
// X1 scratch moved to QR region (breaks false keys<->prenet alias chain;
// every qr slot is written before first read in-loop -> staleness-safe).
// k_epi fuses mel ∥ attn ∥ copy. 12 launches -> 4. Math bit-identical.
// ---------------------------------------------------------------------------

typedef unsigned short us16;
typedef unsigned int u32;
typedef unsigned long long u64;
typedef __attribute__((ext_vector_type(8))) short bf16x8;
typedef __attribute__((ext_vector_type(4))) float f32x4;

#define MFMA16 __builtin_amdgcn_mfma_f32_16x16x32_bf16
#define AGT __HIP_MEMORY_SCOPE_AGENT

__device__ __forceinline__ us16 f2bf(float f){
  u32 u = __builtin_bit_cast(u32, f);
  u += 0x7fffu + ((u >> 16) & 1u);
  return (us16)(u >> 16);
}
__device__ __forceinline__ float bf2f(us16 h){
  return __builtin_bit_cast(float, ((u32)h) << 16);
}
__device__ __forceinline__ float h2f(us16 u){
  _Float16 h = __builtin_bit_cast(_Float16, u); return (float)h;
}
__device__ __forceinline__ us16 f2h(float f){
  _Float16 h = (_Float16)f; return __builtin_bit_cast(us16, h);
}
__device__ __forceinline__ void split3(float v, us16& s0, us16& s1, us16& s2){
  s0 = f2bf(v); float r = v - bf2f(s0);
  s1 = f2bf(r); r -= bf2f(s1);
  s2 = f2bf(r);
}
__device__ __forceinline__ float tanh_fast(float x){
  float e = __expf(-2.f * fmaxf(x, -40.f));
  return (1.f - e) / (1.f + e);
}
__device__ __forceinline__ float sigf(float x){
  return 1.f / (1.f + __expf(-x));
}

__device__ __forceinline__ u32 aload32(const u32* p){
  return __hip_atomic_load(p, __ATOMIC_RELAXED, AGT);
}
__device__ __forceinline__ void astore16(us16* p, us16 v){
  __hip_atomic_store(p, v, __ATOMIC_RELAXED, AGT);
}
__device__ __forceinline__ void astoref(float* p, float v){
  __hip_atomic_store(p, v, __ATOMIC_RELAXED, AGT);
}
__device__ __forceinline__ void sigflag(u32* p, u32 v){
  __hip_atomic_store(p, v, __ATOMIC_RELAXED, AGT);
}
__device__ __forceinline__ void aaddf(float* p, float v){
  __hip_atomic_fetch_add(p, v, __ATOMIC_RELAXED, AGT);
}
__device__ __forceinline__ bf16x8 ld16(const us16* p){
  return *(const bf16x8*)p;
}
// opacity: keep a loaded fragment in regs (non-rematerializable)
__device__ __forceinline__ bf16x8 pin_reg(bf16x8 v){
  f32x4 t = __builtin_bit_cast(f32x4, v);
  asm volatile("" : "+v"(t));
  return __builtin_bit_cast(bf16x8, t);
}
// 8 cached fp32 -> scaled triple-split bf16 fragments (ctx path)
__device__ __forceinline__ void f32_frag3(const float* p, float rs,
                                          bf16x8& f0, bf16x8& f1, bf16x8& f2){
  float4 t0 = *(const float4*)p;
  float4 t1 = *(const float4*)(p + 4);
  float tf[8] = {t0.x, t0.y, t0.z, t0.w, t1.x, t1.y, t1.z, t1.w};
#pragma unroll
  for (int i = 0; i < 8; ++i){
    float v = tf[i] * rs;
    us16 s0, s1, s2; split3(v, s0, s1, s2);
    f0[i] = (short)s0; f1[i] = (short)s1; f2[i] = (short)s2;
  }
}

// ---------------- workspace layout (bytes) ----------------
#define OFF_WTA    0ull            // 3 planes [4096][2048] bf16 (cols permuted u*4+gate)
#define OFF_WQT    50331648ull     // 3 planes [1024][1024] bf16 (Wq^T)
#define OFF_X2P    56623104ull     // 3 planes [32*200][512] bf16 (prenet out)
#define OFF_KEYH   76283904ull     // [8192][1024] fp16 hi
#define OFF_KEYL   93061120ull     // [8192][1024] fp16 lo
#define OFF_HPR    129597440ull    // [201][3][32][1024] bf16 h planes (rolling)
#define OFF_UCR    169115648ull    // [201][32][512] f32 raw ctx sums (rolling, atomics)
#define OFF_SR     182288384ull    // [201][32] f32 softmax sums (rolling; slot0=1)
#define OFF_CB     182314112ull    // [32][1024] f32 c state (block-private)
#define OFF_HF     182445184ull    // [32][1024] f32 final h (plain)
#define OFF_WAPN   182576256ull    // [1536][80] bf16 (Wa@Wp natural)
#define OFF_BPERM  182822016ull    // [4096] f32
#define OFF_ARR    182838400ull    // sync: 6 sets x 8 grp cnt + roots + releases
#define OFF_QR     182870016ull    // [200][32][1024] f32 q (rolling); X1 alias pre-coop
#define TOTAL_WS   209094656ull

#define WTPL 8388608ull
#define WQPL 1048576ull
#define X2PL 3276800ull

// sync sets
#define SA0 0
#define SA1 1
#define SB0 2
#define SB1 3
#define SC0 4
#define SC1 5

// ---------------- device bodies --------------------------------------------
// GEMM <NP=3, AF=1, BF=1, NF=8>: C[M,N] = split3(A f32) @ split3(B f32)
// modes: 0 f32+bias+relu | 1 relu -> x2 triple planes | 2 keys fp16 pair
//        3 fold -> WTA planes (+Wh, perm) | 4 bf16 plain
__device__ void gemm3_dev(char* smem, int bx, int by,
                          const float* __restrict__ Ap, const float* __restrict__ Bp,
                          void* __restrict__ outp, int M, int N, int K, int mode,
                          const float* __restrict__ aux, int ldd){
  us16* At = (us16*)smem;                    // [3][128][72]
  us16* Bt = (us16*)(smem + 55296);          // [3][128][72]
  const int tid = threadIdx.x, wv = tid >> 6, lane = tid & 63;
  const int r0 = lane & 15, kg = lane >> 4;
  const int rb = bx * 128, cb = by * 128;
  f32x4 acc[2][8];
#pragma unroll
  for (int a = 0; a < 2; ++a)
#pragma unroll
    for (int b = 0; b < 8; ++b) acc[a][b] = (f32x4){0.f, 0.f, 0.f, 0.f};

  const int nkt = (K + 63) >> 6;
  for (int kt = 0; kt < nkt; ++kt){
    const int kb = kt * 64;
    for (int e = tid; e < 8192; e += 256){
      int r = e >> 6, k = e & 63, ga = rb + r, gk = kb + k;
      bool ok = (ga < M) && (gk < K);
      float v = ok ? Ap[(size_t)ga * K + gk] : 0.f;
      us16 s0, s1, s2; split3(v, s0, s1, s2);
      At[r * 72 + k] = s0;
      At[(128 + r) * 72 + k] = s1;
      At[(256 + r) * 72 + k] = s2;
    }
    for (int e = tid; e < 8192; e += 256){
      int kr = e >> 7, c = e & 127, gk = kb + kr, gc = cb + c;
      bool ok = (gk < K) && (gc < N);
      float v = ok ? Bp[(size_t)gk * N + gc] : 0.f;
      us16 s0, s1, s2; split3(v, s0, s1, s2);
      Bt[c * 72 + kr] = s0;
      Bt[(128 + c) * 72 + kr] = s1;
      Bt[(256 + c) * 72 + kr] = s2;
    }
    __syncthreads();
#pragma unroll
    for (int kk = 0; kk < 64; kk += 32){
      bf16x8 af[3][2];
#pragma unroll
      for (int p = 0; p < 3; ++p){
        af[p][0] = *(const bf16x8*)&At[(p * 128 + wv * 32 + r0) * 72 + kk + kg * 8];
        af[p][1] = *(const bf16x8*)&At[(p * 128 + wv * 32 + 16 + r0) * 72 + kk + kg * 8];
      }
#pragma unroll
      for (int cf = 0; cf < 8; ++cf){
        bf16x8 bv[3];
#pragma unroll
        for (int p = 0; p < 3; ++p)
          bv[p] = *(const bf16x8*)&Bt[(p * 128 + cf * 16 + r0) * 72 + kk + kg * 8];
#pragma unroll
        for (int rf = 0; rf < 2; ++rf){
          acc[rf][cf] = MFMA16(af[0][rf], bv[0], acc[rf][cf], 0, 0, 0);
          acc[rf][cf] = MFMA16(af[0][rf], bv[1], acc[rf][cf], 0, 0, 0);
          acc[rf][cf] = MFMA16(af[1][rf], bv[0], acc[rf][cf], 0, 0, 0);
          acc[rf][cf] = MFMA16(af[0][rf], bv[2], acc[rf][cf], 0, 0, 0);
          acc[rf][cf] = MFMA16(af[1][rf], bv[1], acc[rf][cf], 0, 0, 0);
          acc[rf][cf] = MFMA16(af[2][rf], bv[0], acc[rf][cf], 0, 0, 0);
        }
      }
    }
    __syncthreads();
  }
  us16* o16 = (us16*)outp; float* of = (float*)outp;
#pragma unroll
  for (int rf = 0; rf < 2; ++rf)
#pragma unroll
    for (int cf = 0; cf < 8; ++cf)
#pragma unroll
      for (int i = 0; i < 4; ++i){
        int r = rb + wv * 32 + rf * 16 + kg * 4 + i;
        int c = cb + cf * 16 + r0;
        if (r >= M || c >= N) continue;
        float v = acc[rf][cf][i];
        if (mode == 0){
          of[(size_t)r * ldd + c] = fmaxf(v + aux[c], 0.f);
        } else if (mode == 1){
          v = fmaxf(v + aux[c], 0.f);
          us16 s0, s1, s2; split3(v, s0, s1, s2);
          size_t b2 = (size_t)r * ldd + c;
          o16[b2] = s0; o16[X2PL + b2] = s1; o16[2 * X2PL + b2] = s2;
        } else if (mode == 2){
          us16 hh = f2h(v); float rem = v - h2f(hh); us16 hl = f2h(rem);
          size_t b2 = (size_t)r * 1024 + c;
          o16[b2] = hh; o16[WTPL + b2] = hl;
        } else if (mode == 3){
          float w = v + (r < 1024 ? aux[(size_t)r * 4096 + c] : 0.f);
          int pc = (c & 1023) * 4 + (c >> 10);
          us16 s0, s1, s2; split3(w, s0, s1, s2);
          size_t b2 = (size_t)pc * 2048 + 512 + r;
          o16[b2] = s0; o16[WTPL + b2] = s1; o16[2 * WTPL + b2] = s2;
        } else {
          o16[(size_t)r * ldd + c] = f2bf(v);
        }
      }
}

// transpose f32 -> 3 bf16 planes (+optional gate perm)
__device__ void transp3_dev(char* smem, int bxi, int byi,
                            const float* __restrict__ src, us16* __restrict__ dst,
                            int srows, int scols, int ldd, long long pstride, int perm){
  float (*tile)[33] = (float(*)[33])smem;
  int bx = bxi * 32, by = byi * 32;
  int tx = threadIdx.x & 31, ty = threadIdx.x >> 5;
#pragma unroll
  for (int i = 0; i < 4; ++i){
    int r = by + ty + i * 8, c = bx + tx;
    tile[ty + i * 8][tx] = (r < srows && c < scols) ? src[(size_t)r * scols + c] : 0.f;
  }
  __syncthreads();
#pragma unroll
  for (int i = 0; i < 4; ++i){
    int c = bx + ty + i * 8;
    int r = by + tx;
    if (c < scols && r < srows){
      int oc = perm ? (((c & 1023) << 2) | (c >> 10)) : c;
      float v = tile[tx][ty + i * 8];
      us16 s0, s1, s2; split3(v, s0, s1, s2);
      size_t base = (size_t)oc * ldd + r;
      dst[base] = s0; dst[(size_t)pstride + base] = s1; dst[2ull * pstride + base] = s2;
    }
  }
}

// ---------------- mega prologue kernel --------------------------------------
struct MegaA {
  const float *inputs, *mem, *W1, *b1, *Wx, *Wh, *bl, *Wm, *Wq, *Wa, *Wp;
  us16 *WTA, *WQT, *KEYH, *WAPN;
  float *X1, *bpm;
  u32 *hpr0; float *ucr, *sr, *cbuf; u32 *arr;
};

__global__ void __launch_bounds__(256) k_mega(MegaA m){
  __shared__ __align__(16) char smem[110592];
  const int blk = blockIdx.x;
  if (blk < 384){                       // fold: 12 x 32, K=1024
    gemm3_dev(smem, blk % 12, blk / 12, m.Wa, m.Wx + (size_t)512 * 4096,
              m.WTA, 1536, 4096, 1024, 3, m.Wh, 0);
  } else if (blk < 396){                // WapN: 12 x 1
    gemm3_dev(smem, blk - 384, 0, m.Wa, m.Wp, m.WAPN, 1536, 80, 1024, 4, nullptr, 80);
  } else if (blk < 796){                // prenet1: 50 x 8 (X1 in QR region)
    int b = blk - 396;
    gemm3_dev(smem, b % 50, b / 50, m.inputs, m.W1, m.X1, 6400, 1024, 80, 0, m.b1, 1024);
  } else if (blk < 1308){               // keys: 64 x 8
    int b = blk - 796;
    gemm3_dev(smem, b % 64, b / 64, m.mem, m.Wm, m.KEYH, 8192, 1024, 512, 2, nullptr, 1024);
  } else if (blk < 2332){               // WQT transpose: 32 x 32
    int b = blk - 1308;
    transp3_dev(smem, b % 32, b / 32, m.Wq, m.WQT, 1024, 1024, 1024, (long long)WQPL, 0);
  } else if (blk < 4380){               // WTA x-part transpose: 128 x 16
    int b = blk - 2332;
    transp3_dev(smem, b % 128, b / 128, m.Wx, m.WTA, 512, 4096, 2048, (long long)WTPL, 1);
  } else {                              // init + bperm: 256 blocks
    u32 id = (u32)(blk - 4380) * 256u + threadIdx.x;
    const u32 gs = 65536u;
    for (u32 i = id; i < 49152u;   i += gs) m.hpr0[i] = 0u;
    for (u32 i = id; i < 3293184u; i += gs) m.ucr[i]  = 0.f;
    for (u32 i = id; i < 6432u;    i += gs) m.sr[i]   = (i < 32u) ? 1.f : 0.f;
    for (u32 i = id; i < 32768u;   i += gs) m.cbuf[i] = 0.f;
    for (u32 i = id; i < 2048u;    i += gs) m.arr[i]  = 0u;
    if (id < 4096u) m.bpm[((id & 1023u) << 2) | (id >> 10)] = m.bl[id];
  }
}

// prenet2 (depends on prenet1): x2 = relu(X1 @ W2 + b2) -> triple planes
struct P2A { const float *X1, *W2, *b2; us16* X2P; };
__global__ void __launch_bounds__(256) k_p2(P2A p){
  __shared__ __align__(16) char smem[110592];
  gemm3_dev(smem, blockIdx.x % 50, blockIdx.x / 50, p.X1, p.W2, p.X2P,
            6400, 512, 1024, 1, p.b2, 512);
}

// ---------------- epilogue: fused gemmE(mel) ∥ gemmE(attn) ∥ copy ----------
__device__ void gemmE_dev(char* smem, int bx, int by, int BF,
                          const us16* __restrict__ hpr, const float* __restrict__ ucr,
                          const float* __restrict__ sr, const void* __restrict__ Bp,
                          float* __restrict__ of, int M, int N, int K, int mode,
                          const float* __restrict__ aux, int ldd, int ro){
  us16* At = (us16*)smem;               // [128][72]
  us16* Bt = (us16*)(smem + 18432);     // [64][72]
  const int tid = threadIdx.x, wv = tid >> 6, lane = tid & 63;
  const int r0 = lane & 15, kg = lane >> 4;
  const int rb = bx * 128, cb = by * 64;
  f32x4 acc[2][4];
#pragma unroll
  for (int a = 0; a < 2; ++a)
#pragma unroll
    for (int b = 0; b < 4; ++b) acc[a][b] = (f32x4){0.f, 0.f, 0.f, 0.f};

  const int nkt = (K + 63) >> 6;
  for (int kt = 0; kt < nkt; ++kt){
    const int kb = kt * 64;
    for (int e = tid; e < 8192; e += 256){
      int r = e >> 6, k = e & 63, ga = rb + r, gk = kb + k;
      us16 v = 0;
      if (ga < M && gk < K){
        int row = ro + ga, t = row >> 5, b = row & 31;
        if (gk < 1024){
          v = hpr[(size_t)t * 98304 + b * 1024 + gk];
        } else {
          float rs = 1.f / sr[(size_t)t * 32 + b];
          v = f2bf(ucr[(size_t)t * 16384 + b * 512 + (gk - 1024)] * rs);
        }
      }
      At[r * 72 + k] = v;
    }
    for (int e = tid; e < 4096; e += 256){
      int kr = e >> 6, c = e & 63, gk = kb + kr, gc = cb + c;
      bool ok = (gk < K) && (gc < N);
      if (BF == 1){
        float v = ok ? ((const float*)Bp)[(size_t)gk * N + gc] : 0.f;
        Bt[c * 72 + kr] = f2bf(v);
      } else {
        Bt[c * 72 + kr] = ok ? ((const us16*)Bp)[(size_t)gk * N + gc] : (us16)0;
      }
    }
    __syncthreads();
#pragma unroll
    for (int kk = 0; kk < 64; kk += 32){
      bf16x8 a0 = *(const bf16x8*)&At[(wv * 32 + r0) * 72 + kk + kg * 8];
      bf16x8 a1 = *(const bf16x8*)&At[(wv * 32 + 16 + r0) * 72 + kk + kg * 8];
#pragma unroll
      for (int cf = 0; cf < 4; ++cf){
        bf16x8 bv = *(const bf16x8*)&Bt[(cf * 16 + r0) * 72 + kk + kg * 8];
        acc[0][cf] = MFMA16(a0, bv, acc[0][cf], 0, 0, 0);
        acc[1][cf] = MFMA16(a1, bv, acc[1][cf], 0, 0, 0);
      }
    }
    __syncthreads();
  }
#pragma unroll
  for (int rf = 0; rf < 2; ++rf)
#pragma unroll
    for (int cf = 0; cf < 4; ++cf)
#pragma unroll
      for (int i = 0; i < 4; ++i){
        int r = rb + wv * 32 + rf * 16 + kg * 4 + i;
        int c = cb + cf * 16 + r0;
        if (r >= M || c >= N) continue;
        float v = acc[rf][cf][i];
        if (mode == 5){
          of[((size_t)(r & 31) * 200 + (r >> 5)) * 80 + c] = v + aux[c];
        } else {
          of[(size_t)r * ldd + c] = v;
        }
      }
}

struct EpiA {
  const us16 *hpr; const float *ucr, *sr;
  const us16 *WAPN; const float *Wa, *bp, *hf, *cb;
  float *out;
};
__global__ void __launch_bounds__(256) k_epi(EpiA e){
  __shared__ __align__(16) char smem[27648];
  const int blk = blockIdx.x;
  if (blk < 100){                       // mel: 50 x 2, ro=32
    gemmE_dev(smem, blk % 50, blk / 50, 0, e.hpr, e.ucr, e.sr, e.WAPN,
              e.out, 6400, 80, 1536, 5, e.bp, 0, 32);
  } else if (blk < 116){                // attn: 1 x 16, ro=6400
    gemmE_dev(smem, 0, blk - 100, 1, e.hpr, e.ucr, e.sr, e.Wa,
              e.out + 577536, 32, 1024, 1536, 6, nullptr, 1024, 6400);
  } else {                              // copy h,c: 128 blocks
    int i = (blk - 116) * 256 + threadIdx.x;
    if (i < 32768){
      e.out[512000 + i] = e.hf[i];
      e.out[544768 + i] = e.cb[i];
    }
  }
}

// ---------------- split arrive / wait (two-level, last-arriver-releases) ----
__device__ __forceinline__ void arrv(u32* arr, int set, u32 ng, u32 ep, int tid, int blk){
  __syncthreads();
  if (tid == 0){
    int g = (blk >> 5) & 7;
    u32 old = __hip_atomic_fetch_add(&arr[(set * 8 + g) * 32], 1u, __ATOMIC_RELAXED, AGT);
    if (old == 32u * ep - 1u){
      u32 r = __hip_atomic_fetch_add(&arr[(48 + set) * 32], 1u, __ATOMIC_RELAXED, AGT);
      if (r == ng * ep - 1u)
        sigflag(&arr[(56 + set) * 32], ep);
    }
  }
}
__device__ __forceinline__ void waitrel(u32* arr, int set, u32 ep, int tid){
  if (tid == 0){
    while (aload32(&arr[(56 + set) * 32]) < ep) __builtin_amdgcn_s_sleep(2);
    __builtin_amdgcn_sched_barrier(0);
  }
  __syncthreads();
}

// ---------------- persistent scan kernel (identical to R15/R17) -------------
struct CoopA {
  const us16 *wta, *wqt, *x2p, *kh, *kl;
  const float *mem, *vatt, *bperm;
  us16 *hpr;
  float *ucr, *sr, *qr, *cbuf, *hf32;
  u32 *arr;
};

__global__ void __launch_bounds__(512, 1) k_coop(CoopA a){
  __shared__ us16 khi[32][1024];
  __shared__ us16 klo[32][1024];
  __shared__ float zp[8][512];
  __shared__ float esc[16];

  __builtin_amdgcn_fence(__ATOMIC_ACQUIRE, "agent");

  const int tid = threadIdx.x, blk = blockIdx.x;
  const int wv = tid >> 6, lane = tid & 63;
  const int r0 = lane & 15, kg = lane >> 4;
  const int b16 = blk >> 4, s0c = (blk & 15) * 16;
  const int colbase = blk * 16;
  const int u0 = lane * 16;

  bf16x8 wr[8][3];
#pragma unroll
  for (int ks = 0; ks < 8; ++ks){
    const size_t wb = (size_t)(colbase + r0) * 2048 + (size_t)wv * 256 + ks * 32 + kg * 8;
#pragma unroll
    for (int p = 0; p < 3; ++p)
      wr[ks][p] = pin_reg(*(const bf16x8*)&a.wta[(size_t)p * WTPL + wb]);
  }

  {
    for (int i = tid; i < 4096; i += 512){
      int r = i >> 7, c8 = (i & 127) * 8;
      int gb = (r < 16) ? b16 : (16 + b16);
      int s  = s0c + (r & 15);
      const size_t kb = ((size_t)(gb * 256 + s)) * 1024 + c8;
      *(bf16x8*)&khi[r][c8] = *(const bf16x8*)&a.kh[kb];
      *(bf16x8*)&klo[r][c8] = *(const bf16x8*)&a.kl[kb];
    }
  }
  __syncthreads();

  auto phaseA = [&](int g, int t){
    const int gr = g * 16;
    f32x4 acc = (f32x4){0.f, 0.f, 0.f, 0.f};
    float rsv = (wv >= 6) ? 1.f / a.sr[(size_t)t * 32 + gr + r0] : 0.f;
#pragma unroll
    for (int ks = 0; ks < 8; ++ks){
      const int kf = wv * 256 + ks * 32 + kg * 8;
      bf16x8 w0 = wr[ks][0], w1 = wr[ks][1], w2 = wr[ks][2];
      bf16x8 a0, a1, a2;
      if (wv < 2){
        const size_t xb = ((size_t)(gr + r0) * 200 + t) * 512 + kf;
        a0 = *(const bf16x8*)&a.x2p[xb];
        a1 = *(const bf16x8*)&a.x2p[X2PL + xb];
        a2 = *(const bf16x8*)&a.x2p[2 * X2PL + xb];
      } else if (wv < 6){
        const int hk = kf - 512;
        const us16* hb = a.hpr + (size_t)t * 98304 + (size_t)(gr + r0) * 1024 + hk;
        a0 = ld16(hb); a1 = ld16(hb + 32768); a2 = ld16(hb + 65536);
      } else {
        const int ek = kf - 1536;
        const float* up = a.ucr + (size_t)t * 16384 + (size_t)(gr + r0) * 512 + ek;
        f32_frag3(up, rsv, a0, a1, a2);
      }
      acc = MFMA16(a0, w0, acc, 0,0,0); acc = MFMA16(a0, w1, acc, 0,0,0);
      acc = MFMA16(a1, w0, acc, 0,0,0); acc = MFMA16(a0, w2, acc, 0,0,0);
      acc = MFMA16(a1, w1, acc, 0,0,0); acc = MFMA16(a2, w0, acc, 0,0,0);
    }
#pragma unroll
    for (int i = 0; i < 4; ++i)
      zp[wv][(kg * 4 + i) * 16 + r0] = acc[i];
    __syncthreads();
    float z = 0.f;
    if (tid < 256){
#pragma unroll
      for (int w = 0; w < 8; ++w) z += zp[w][tid];
      z += a.bperm[colbase + (tid & 15)];
    }
    __syncthreads();
    if (tid < 256) zp[0][tid] = z;
    __syncthreads();
    if (tid < 64){
      int bl = tid >> 2, ul = tid & 3, u = blk * 4 + ul;
      int b = gr + bl;
      float zi = zp[0][bl * 16 + ul * 4 + 0];
      float zf = zp[0][bl * 16 + ul * 4 + 1];
      float zg = zp[0][bl * 16 + ul * 4 + 2];
      float zo = zp[0][bl * 16 + ul * 4 + 3];
      float co = a.cbuf[b * 1024 + u];
      float cn = sigf(zf) * co + sigf(zi) * tanh_fast(zg);
      float hn = sigf(zo) * tanh_fast(cn);
      a.cbuf[b * 1024 + u] = cn;
      a.hf32[b * 1024 + u] = hn;
      us16 s0, s1, s2; split3(hn, s0, s1, s2);
      us16* hb = a.hpr + (size_t)(t + 1) * 98304 + b * 1024 + u;
      astore16(hb, s0);
      astore16(hb + 32768, s1);
      astore16(hb + 65536, s2);
    }
  };

  auto phaseB = [&](int g, int t, int colb){
    const int gr = g * 16;
    f32x4 acc = (f32x4){0.f, 0.f, 0.f, 0.f};
#pragma unroll
    for (int ks = 0; ks < 4; ++ks){
      const int kf = wv * 128 + ks * 32 + kg * 8;
      const size_t wb = (size_t)(colb + r0) * 1024 + kf;
      bf16x8 w0 = *(const bf16x8*)&a.wqt[wb];
      bf16x8 w1 = *(const bf16x8*)&a.wqt[WQPL + wb];
      bf16x8 w2 = *(const bf16x8*)&a.wqt[2 * WQPL + wb];
      const us16* hb = a.hpr + (size_t)(t + 1) * 98304 + (size_t)(gr + r0) * 1024 + kf;
      bf16x8 a0 = ld16(hb), a1 = ld16(hb + 32768), a2 = ld16(hb + 65536);
      acc = MFMA16(a0, w0, acc, 0,0,0); acc = MFMA16(a0, w1, acc, 0,0,0);
      acc = MFMA16(a1, w0, acc, 0,0,0); acc = MFMA16(a0, w2, acc, 0,0,0);
      acc = MFMA16(a1, w1, acc, 0,0,0); acc = MFMA16(a2, w0, acc, 0,0,0);
    }
#pragma unroll
    for (int i = 0; i < 4; ++i)
      zp[wv][(kg * 4 + i) * 16 + r0] = acc[i];
    __syncthreads();
    if (tid < 256){
      float q = 0.f;
#pragma unroll
      for (int w = 0; w < 8; ++w) q += zp[w][tid];
      astoref(&a.qr[(size_t)t * 32768 + (size_t)(gr + (tid >> 4)) * 1024 + colb + (tid & 15)], q);
    }
  };

  auto phaseC = [&](int g, int t){
    const int b = g * 16 + b16;
    float qv[16], vv[16];
    {
      const float* qp = a.qr + (size_t)t * 32768 + (size_t)b * 1024 + u0;
      float4 q0 = *(const float4*)qp;
      float4 q1 = *(const float4*)(qp + 4);
      float4 q2 = *(const float4*)(qp + 8);
      float4 q3 = *(const float4*)(qp + 12);
      qv[0]=q0.x; qv[1]=q0.y; qv[2]=q0.z; qv[3]=q0.w;
      qv[4]=q1.x; qv[5]=q1.y; qv[6]=q1.z; qv[7]=q1.w;
      qv[8]=q2.x; qv[9]=q2.y; qv[10]=q2.z; qv[11]=q2.w;
      qv[12]=q3.x; qv[13]=q3.y; qv[14]=q3.z; qv[15]=q3.w;
      float4 v0 = *(const float4*)(a.vatt + u0);
      float4 v1 = *(const float4*)(a.vatt + u0 + 4);
      float4 v2 = *(const float4*)(a.vatt + u0 + 8);
      float4 v3 = *(const float4*)(a.vatt + u0 + 12);
      vv[0]=v0.x; vv[1]=v0.y; vv[2]=v0.z; vv[3]=v0.w;
      vv[4]=v1.x; vv[5]=v1.y; vv[6]=v1.z; vv[7]=v1.w;
      vv[8]=v2.x; vv[9]=v2.y; vv[10]=v2.z; vv[11]=v2.w;
      vv[12]=v3.x; vv[13]=v3.y; vv[14]=v3.z; vv[15]=v3.w;
    }
#pragma unroll
    for (int m = 0; m < 2; ++m){
      const int sl = wv * 2 + m;
      const int kr = g * 16 + sl;
      bf16x8 h0 = *(const bf16x8*)&khi[kr][u0];
      bf16x8 h1 = *(const bf16x8*)&khi[kr][u0 + 8];
      bf16x8 l0 = *(const bf16x8*)&klo[kr][u0];
      bf16x8 l1 = *(const bf16x8*)&klo[kr][u0 + 8];
      float part = 0.f;
#pragma unroll
      for (int j = 0; j < 8; ++j){
        float kva = h2f((us16)h0[j]) + h2f((us16)l0[j]);
        part += vv[j] * tanh_fast(kva + qv[j]);
        float kvb = h2f((us16)h1[j]) + h2f((us16)l1[j]);
        part += vv[8 + j] * tanh_fast(kvb + qv[8 + j]);
      }
#pragma unroll
      for (int off = 32; off; off >>= 1) part += __shfl_xor(part, off);
      if (lane == 0) esc[sl] = __expf(part);    // max-free softmax
    }
    __syncthreads();
    if (tid == 0){
      float bs = 0.f;
#pragma unroll
      for (int i = 0; i < 16; ++i) bs += esc[i];
      aaddf(&a.sr[(size_t)(t + 1) * 32 + b], bs);
    }
    {
      float ac0 = 0.f, ac1 = 0.f;
      const float* mrow = a.mem + ((size_t)(b * 256 + s0c)) * 512 + tid;
#pragma unroll
      for (int j = 0; j < 16; j += 2){
        ac0 += esc[j]     * mrow[(size_t)j * 512];
        ac1 += esc[j + 1] * mrow[(size_t)(j + 1) * 512];
      }
      aaddf(&a.ucr[(size_t)(t + 1) * 16384 + b * 512 + tid], ac0 + ac1);
    }
    __syncthreads();
  };

  for (int t = 0; t < 200; ++t){
    const u32 ep = (u32)(t + 1);
    waitrel(a.arr, SC0, (u32)t, tid);
    phaseA(0, t);
    arrv(a.arr, SA0, 8, ep, tid, blk);
    waitrel(a.arr, SC1, (u32)t, tid);
    phaseA(1, t);
    arrv(a.arr, SA1, 8, ep, tid, blk);
    if (blk < 64){
      waitrel(a.arr, SA0, ep, tid);
      phaseB(0, t, blk * 16);
      arrv(a.arr, SB0, 2, ep, tid, blk);
    } else if (blk < 128){
      waitrel(a.arr, SA1, ep, tid);
      phaseB(1, t, (blk - 64) * 16);
      arrv(a.arr, SB1, 2, ep, tid, blk);
    }
    waitrel(a.arr, SB0, ep, tid);
    phaseC(0, t);
    arrv(a.arr, SC0, 8, ep, tid, blk);
    waitrel(a.arr, SB1, ep, tid);
    phaseC(1, t);
    arrv(a.arr, SC1, 8, ep, tid, blk);
  }
}

// ---------------------------------------------------------------------------
extern "C" void kernel_launch(void* const* d_in, const int* in_sizes, int n_in,
                              void* d_out, int out_size, void* d_ws, size_t ws_size,
                              hipStream_t stream){
  const float* inputs = (const float*)d_in[0];
  const float* memory = (const float*)d_in[1];
  const float* W1     = (const float*)d_in[2];
  const float* b1     = (const float*)d_in[3];
  const float* W2     = (const float*)d_in[4];
  const float* b2     = (const float*)d_in[5];
  const float* Wx     = (const float*)d_in[6];
  const float* Wh     = (const float*)d_in[7];
  const float* b_lstm = (const float*)d_in[8];
  const float* Wm     = (const float*)d_in[9];
  const float* Wq     = (const float*)d_in[10];
  const float* v_att  = (const float*)d_in[11];
  const float* Wa     = (const float*)d_in[12];
  const float* Wp     = (const float*)d_in[13];
  const float* bp     = (const float*)d_in[14];
  float* out = (float*)d_out;
  char* ws = (char*)d_ws;
  if (ws_size < TOTAL_WS) return;

  us16* WTA    = (us16*)(ws + OFF_WTA);
  us16* WQT    = (us16*)(ws + OFF_WQT);
  us16* X2P    = (us16*)(ws + OFF_X2P);
  us16* KEYH   = (us16*)(ws + OFF_KEYH);
  us16* HPR    = (us16*)(ws + OFF_HPR);
  float* UCR   = (float*)(ws + OFF_UCR);
  float* SR    = (float*)(ws + OFF_SR);
  float* QR    = (float*)(ws + OFF_QR);
  float* X1    = (float*)(ws + OFF_QR);   // alias: dead before coop; qr slots
  float* CB    = (float*)(ws + OFF_CB);   //        rewritten before first read
  float* HF    = (float*)(ws + OFF_HF);
  us16* WAPN   = (us16*)(ws + OFF_WAPN);
  float* BPM   = (float*)(ws + OFF_BPERM);
  u32*  ARR    = (u32*)(ws + OFF_ARR);

  MegaA ma;
  ma.inputs = inputs; ma.mem = memory; ma.W1 = W1; ma.b1 = b1; ma.Wx = Wx;
  ma.Wh = Wh; ma.bl = b_lstm; ma.Wm = Wm; ma.Wq = Wq; ma.Wa = Wa; ma.Wp = Wp;
  ma.WTA = WTA; ma.WQT = WQT; ma.KEYH = KEYH; ma.WAPN = WAPN;
  ma.X1 = X1; ma.bpm = BPM;
  ma.hpr0 = (u32*)HPR; ma.ucr = UCR; ma.sr = SR; ma.cbuf = CB; ma.arr = ARR;
  k_mega<<<4636, 256, 0, stream>>>(ma);

  P2A p2; p2.X1 = X1; p2.W2 = W2; p2.b2 = b2; p2.X2P = X2P;
  k_p2<<<200, 256, 0, stream>>>(p2);

  CoopA ca;
  ca.wta = WTA; ca.wqt = WQT; ca.x2p = X2P; ca.kh = KEYH; ca.kl = KEYH + WTPL;
  ca.mem = memory; ca.vatt = v_att; ca.bperm = BPM;
  ca.hpr = HPR; ca.ucr = UCR; ca.sr = SR;
  ca.qr = QR; ca.cbuf = CB; ca.hf32 = HF; ca.arr = ARR;
  void* args[] = {(void*)&ca};
  hipLaunchCooperativeKernel((const void*)k_coop, dim3(256), dim3(512), args, 0, stream);

  EpiA ea;
  ea.hpr = HPR; ea.ucr = UCR; ea.sr = SR; ea.WAPN = WAPN; ea.Wa = Wa;
  ea.bp = bp; ea.hf = HF; ea.cb = CB; ea.out = out;
  k_epi<<<244, 256, 0, stream>>>(ea);
}